// Round 6
// baseline (1175.761 us; speedup 1.0000x reference)
//
#include <hip/hip_runtime.h>

#define BB 16
#define CC 32
#define KK 4
#define CKD 128     // C*K
#define NN 8192
#define NLEV 13
#define AL 128      // ALPHA (weight mode-axis storage stride)

typedef unsigned short u16;
typedef __attribute__((ext_vector_type(8))) short bf16x8;
typedef __attribute__((ext_vector_type(8))) unsigned short ushort8;
typedef __attribute__((ext_vector_type(4))) float f32x4;

struct LevTab { int off[NLEV]; int n[NLEV]; int l[NLEV]; int total; };
struct MixTab2 { long long off[NLEV]; int l[NLEV]; int mcum[NLEV]; };

__device__ __forceinline__ u16 f2bh(float x) {
  union { float f; unsigned u; } v; v.f = x;
  unsigned r = (v.u + 0x7fffu + ((v.u >> 16) & 1u)) >> 16;
  return (u16)r;
}
__device__ __forceinline__ float bh2f(u16 h) {
  union { unsigned u; float f; } v; v.u = ((unsigned)h) << 16; return v.f;
}
__device__ __forceinline__ bf16x8 ld8t(const u16* p, int rem, bool fast) {
  if (fast && rem >= 8) return *(const bf16x8*)p;
  union { bf16x8 v; u16 e[8]; } u;
  #pragma unroll
  for (int i = 0; i < 8; i++) u.e[i] = 0;
  for (int i = 0; i < 8; i++) if (i < rem) u.e[i] = p[i];
  return u.v;
}

// inverse A planes [j][m] (sin NEGATED) + forward planes [m][j] (sin positive)
__global__ void twiddle_fill_k(u16* __restrict__ tjch, u16* __restrict__ tjcl,
                               u16* __restrict__ tjsh, u16* __restrict__ tjsl,
                               u16* __restrict__ tch, u16* __restrict__ tcl,
                               u16* __restrict__ tsh, u16* __restrict__ tsl, LevTab t) {
  int idx = blockIdx.x * blockDim.x + threadIdx.x;
  if (idx >= t.total) return;
  int lev = 0;
  for (int q = 1; q < NLEV; q++) lev = (idx >= t.off[q]) ? q : lev;
  int r = idx - t.off[lev];
  int n = t.n[lev], l = t.l[lev];
  int j = r / l, m = r - j * l;
  long long pp = ((long long)j * (long long)m) % n;
  float ang = (float)((double)pp * (6.283185307179586476925286766559 / (double)n));
  float s, c;
  sincosf(ang, &s, &c);
  // inverse planes, [j][m] = contiguous at idx
  size_t oj = (size_t)idx;
  u16 h = f2bh(c); tjch[oj] = h; tjcl[oj] = f2bh(c - bh2f(h));
  float ns = -s;
  h = f2bh(ns); tjsh[oj] = h; tjsl[oj] = f2bh(ns - bh2f(h));
  // forward planes, [m][j]
  size_t om = (size_t)t.off[lev] + (size_t)m * n + j;
  h = f2bh(c); tch[om] = h; tcl[om] = f2bh(c - bh2f(h));
  h = f2bh(s); tsh[om] = h; tsl[om] = f2bh(s - bh2f(h));
}

// fused decompose + transpose/convert:
// x:(B,2nh,CKD) fp32 -> s:(B,nh,CKD) fp32 (next level input)
//                    -> dh/dl/sh/sl: (B,CKD,nh) bf16 split planes (MFMA operands)
__global__ void decomp_t_k(const float* __restrict__ xin, float* __restrict__ sout,
                           u16* __restrict__ dh, u16* __restrict__ dl,
                           u16* __restrict__ sh, u16* __restrict__ sl,
                           const float* __restrict__ ecs, const float* __restrict__ ecd,
                           int nh) {
  int b = blockIdx.y;
  int j0 = blockIdx.x << 6;
  int t = threadIdx.x;
  int c = t & 31, j8 = t >> 5;
  int jbase = j0 + (j8 << 3);
  float s8[4][8], d8[4][8];
  #pragma unroll
  for (int jj = 0; jj < 8; jj++) {
    int j = jbase + jj;
    float sv[4] = {0.f,0.f,0.f,0.f}, dv[4] = {0.f,0.f,0.f,0.f};
    if (j < nh) {
      size_t ib = (((size_t)b * 2 * nh + 2 * j) * CC + c) * KK;
      float4 xe = *(const float4*)(xin + ib);
      float4 xo = *(const float4*)(xin + ib + CC * KK);
      float xa[8] = {xe.x, xe.y, xe.z, xe.w, xo.x, xo.y, xo.z, xo.w};
      #pragma unroll
      for (int p = 0; p < 8; p++) {
        float v = xa[p];
        #pragma unroll
        for (int k = 0; k < 4; k++) {
          sv[k] = fmaf(v, ecs[p*4+k], sv[k]);
          dv[k] = fmaf(v, ecd[p*4+k], dv[k]);
        }
      }
      size_t ob = (((size_t)b * nh + j) * CC + c) * KK;
      *(float4*)(sout + ob) = make_float4(sv[0], sv[1], sv[2], sv[3]);
    }
    #pragma unroll
    for (int k = 0; k < 4; k++) { s8[k][jj] = sv[k]; d8[k][jj] = dv[k]; }
  }
  if (jbase < nh) {
    bool full = (jbase + 8 <= nh);
    #pragma unroll
    for (int k = 0; k < 4; k++) {
      int i = (c << 2) + k;
      size_t rb = ((size_t)b * CKD + i) * nh + jbase;
      ushort8 vh, vl, wh, wl;
      #pragma unroll
      for (int jj = 0; jj < 8; jj++) {
        float dvv = d8[k][jj];
        u16 h = f2bh(dvv); vh[jj] = h; vl[jj] = f2bh(dvv - bh2f(h));
        float svv = s8[k][jj];
        h = f2bh(svv); wh[jj] = h; wl[jj] = f2bh(svv - bh2f(h));
      }
      if (full) {
        *(ushort8*)(dh + rb) = vh; *(ushort8*)(dl + rb) = vl;
        *(ushort8*)(sh + rb) = wh; *(ushort8*)(sl + rb) = wl;
      } else {
        int lim = nh - jbase;
        for (int jj = 0; jj < lim; jj++) {
          dh[rb+jj] = vh[jj]; dl[rb+jj] = vl[jj];
          sh[rb+jj] = wh[jj]; sl[rb+jj] = wl[jj];
        }
      }
    }
  }
}

// ---- MFMA forward DFT (split-bf16, 3 mfma per product) ----
__global__ void __launch_bounds__(256)
fwd_mfma_k(const u16* __restrict__ dhp, const u16* __restrict__ dlp,
           const u16* __restrict__ shp, const u16* __restrict__ slp,
           const u16* __restrict__ tch, const u16* __restrict__ tcl,
           const u16* __restrict__ tsh, const u16* __restrict__ tsl,
           float2* __restrict__ Dp, float2* __restrict__ Sp,
           int n, int l, int P, int chunk) {
  __shared__ u16 Ts[4][64][40];    // cos_hi, cos_lo, sin_hi, sin_lo  [m][j]
  __shared__ u16 Vs[2][128][40];   // v_hi, v_lo                      [i][j]
  int zz = blockIdx.z;
  int srcs = (zz >= P) ? 1 : 0;
  int ks = zz - srcs * P;
  int b = blockIdx.y;
  int m0 = blockIdx.x << 6;
  const u16* vhp = srcs ? shp : dhp;
  const u16* vlp = srcs ? slp : dlp;
  float2* __restrict__ dst = (srcs ? Sp : Dp) + (size_t)ks * ((size_t)BB * CKD * l);
  int kstart = ks * chunk;
  int kcnt = n - kstart; if (kcnt > chunk) kcnt = chunk; if (kcnt < 0) kcnt = 0;
  int kmax = kstart + kcnt;
  int t = threadIdx.x, ln = t & 63, w = t >> 6;
  int wm = (w >> 1) << 5, wi = (w & 1) << 6;
  f32x4 accr[2][4], acci[2][4];
  #pragma unroll
  for (int a = 0; a < 2; a++)
    #pragma unroll
    for (int d = 0; d < 4; d++) {
      accr[a][d] = (f32x4){0.f,0.f,0.f,0.f};
      acci[a][d] = (f32x4){0.f,0.f,0.f,0.f};
    }
  const u16* tp0 = tch; const u16* tp1 = tcl; const u16* tp2 = tsh; const u16* tp3 = tsl;

  for (int js = 0; js < kcnt; js += 32) {
    #pragma unroll
    for (int it = 0; it < 4; it++) {     // stage T: 4 planes x 64 rows x 4 chunks
      int idx = t + (it << 8);
      int p = idx >> 8, r = (idx >> 2) & 63, jc = idx & 3;
      int jg = kstart + js + (jc << 3);
      ushort8 v = {0,0,0,0,0,0,0,0};
      int mrow = m0 + r;
      if (mrow < l && jg < kmax) {
        const u16* sp = (p == 0 ? tp0 : p == 1 ? tp1 : p == 2 ? tp2 : tp3)
                        + (size_t)mrow * n + jg;
        if (jg + 8 <= kmax) v = *(const ushort8*)sp;
        else { for (int e = 0; e < 8; e++) if (jg + e < kmax) v[e] = sp[e]; }
      }
      *(ushort8*)&Ts[p][r][jc << 3] = v;
    }
    #pragma unroll
    for (int it = 0; it < 4; it++) {     // stage V: 2 planes x 128 rows x 4 chunks
      int idx = t + (it << 8);
      int p = idx >> 9, r = (idx >> 2) & 127, jc = idx & 3;
      int jg = kstart + js + (jc << 3);
      ushort8 v = {0,0,0,0,0,0,0,0};
      if (jg < kmax) {
        const u16* bp = (p ? vlp : vhp) + ((size_t)b * CKD + r) * n + jg;
        if (jg + 8 <= kmax) v = *(const ushort8*)bp;
        else { for (int e = 0; e < 8; e++) if (jg + e < kmax) v[e] = bp[e]; }
      }
      *(ushort8*)&Vs[p][r][jc << 3] = v;
    }
    __syncthreads();
    int ac = (ln >> 4) << 3;
    #pragma unroll
    for (int fm = 0; fm < 2; fm++) {
      int ar = wm + (fm << 4) + (ln & 15);
      bf16x8 ach = *(const bf16x8*)&Ts[0][ar][ac];
      bf16x8 acl = *(const bf16x8*)&Ts[1][ar][ac];
      bf16x8 ash = *(const bf16x8*)&Ts[2][ar][ac];
      bf16x8 asl = *(const bf16x8*)&Ts[3][ar][ac];
      #pragma unroll
      for (int fi = 0; fi < 4; fi++) {
        int br = wi + (fi << 4) + (ln & 15);
        bf16x8 bh = *(const bf16x8*)&Vs[0][br][ac];
        bf16x8 bl = *(const bf16x8*)&Vs[1][br][ac];
        accr[fm][fi] = __builtin_amdgcn_mfma_f32_16x16x32_bf16(ach, bh, accr[fm][fi], 0, 0, 0);
        accr[fm][fi] = __builtin_amdgcn_mfma_f32_16x16x32_bf16(ach, bl, accr[fm][fi], 0, 0, 0);
        accr[fm][fi] = __builtin_amdgcn_mfma_f32_16x16x32_bf16(acl, bh, accr[fm][fi], 0, 0, 0);
        acci[fm][fi] = __builtin_amdgcn_mfma_f32_16x16x32_bf16(ash, bh, acci[fm][fi], 0, 0, 0);
        acci[fm][fi] = __builtin_amdgcn_mfma_f32_16x16x32_bf16(ash, bl, acci[fm][fi], 0, 0, 0);
        acci[fm][fi] = __builtin_amdgcn_mfma_f32_16x16x32_bf16(asl, bh, acci[fm][fi], 0, 0, 0);
      }
    }
    __syncthreads();
  }
  #pragma unroll
  for (int fm = 0; fm < 2; fm++)
    #pragma unroll
    for (int fi = 0; fi < 4; fi++) {
      int i = wi + (fi << 4) + (ln & 15);
      int mb = m0 + wm + (fm << 4) + ((ln >> 4) << 2);
      #pragma unroll
      for (int rg = 0; rg < 4; rg++) {
        int m = mb + rg;
        if (m < l)
          dst[((size_t)b * l + m) * CKD + i] = make_float2(accr[fm][fi][rg], -acci[fm][fi][rg]);
      }
    }
}

// sum P partial spectra (scratch) into compact Dall/Sall slots
__global__ void reduce_k(float4* __restrict__ dD, float4* __restrict__ dS,
                         const float4* __restrict__ pD, const float4* __restrict__ pS,
                         int cnt4, int P) {
  int idx = blockIdx.x * blockDim.x + threadIdx.x;
  if (idx >= 2 * cnt4) return;
  const float4* src = (idx < cnt4) ? pD : pS;
  float4* dst = (idx < cnt4) ? dD : dS;
  int e = (idx < cnt4) ? idx : idx - cnt4;
  float4 a = src[e];
  for (int p = 1; p < P; p++) {
    float4 v = src[(size_t)p * cnt4 + e];
    a.x += v.x; a.y += v.y; a.z += v.z; a.w += v.w;
  }
  dst[e] = a;
}

// weight transpose: W[i][o][m] (re,im separate) -> Wt[m][i][o] interleaved float2
__global__ void wtr_k(const float* __restrict__ Ar, const float* __restrict__ Ai,
                      const float* __restrict__ Br, const float* __restrict__ Bi,
                      const float* __restrict__ Cr, const float* __restrict__ Ci,
                      float2* __restrict__ WtA, float2* __restrict__ WtB,
                      float2* __restrict__ WtC) {
  __shared__ float2 Ts[32][130];
  int i = blockIdx.x;
  int o0 = blockIdx.y << 5;
  int z = blockIdx.z;
  const float* Wr = (z == 0) ? Ar : ((z == 1) ? Br : Cr);
  const float* Wi = (z == 0) ? Ai : ((z == 1) ? Bi : Ci);
  float2* Wt = (z == 0) ? WtA : ((z == 1) ? WtB : WtC);
  int tid = threadIdx.x;
  {
    int o = tid >> 3, m0 = (tid & 7) << 4;
    const float* rp = Wr + ((size_t)i * CKD + o0 + o) * AL + m0;
    const float* ip = Wi + ((size_t)i * CKD + o0 + o) * AL + m0;
    #pragma unroll
    for (int r = 0; r < 4; r++) {
      float4 vr = *(const float4*)(rp + r * 4);
      float4 vi = *(const float4*)(ip + r * 4);
      Ts[o][m0 + r*4 + 0] = make_float2(vr.x, vi.x);
      Ts[o][m0 + r*4 + 1] = make_float2(vr.y, vi.y);
      Ts[o][m0 + r*4 + 2] = make_float2(vr.z, vi.z);
      Ts[o][m0 + r*4 + 3] = make_float2(vr.w, vi.w);
    }
  }
  __syncthreads();
  {
    int m = tid >> 1, oh = (tid & 1) << 4;
    float2* wp = Wt + ((size_t)m * CKD + i) * CKD + o0 + oh;
    #pragma unroll
    for (int r = 0; r < 16; r += 2) {
      float2 e0 = Ts[oh + r][m];
      float2 e1 = Ts[oh + r + 1][m];
      *(float4*)(wp + r) = make_float4(e0.x, e0.y, e1.x, e1.y);
    }
  }
}

// batched per-(lev,m) complex GEMM; outputs written as 8 split-bf16 planes [b][m][o]
// plane order: 0..3 = U rh,rl,ih,il ; 4..7 = V rh,rl,ih,il ; plane stride ps
__global__ void __launch_bounds__(256)
mix2_k(const float2* __restrict__ Dall, const float2* __restrict__ Sall,
       const float2* __restrict__ WA, const float2* __restrict__ WB,
       const float2* __restrict__ WC,
       u16* __restrict__ Up8, long long ps, MixTab2 mt) {
  __shared__ __align__(16) float2 Dl[CKD][BB];
  __shared__ __align__(16) float2 Sl[CKD][BB];
  int bx = blockIdx.x;
  int lev = 0;
  #pragma unroll
  for (int q = 1; q < NLEV; q++) lev = (bx >= mt.mcum[q]) ? q : lev;
  int m = bx - mt.mcum[lev];
  int l = mt.l[lev];
  const float2* __restrict__ D = Dall + mt.off[lev];
  const float2* __restrict__ S = Sall + mt.off[lev];
  u16* __restrict__ Ub = Up8 + mt.off[lev];
  int tid = threadIdx.x;
  int o = tid & (CKD - 1), bh = tid >> 7;
  {
    int bq = tid & 15, i0 = (tid >> 4) << 3;
    const float2* Db = D + ((size_t)bq * l + m) * CKD + i0;
    const float2* Sb = S + ((size_t)bq * l + m) * CKD + i0;
    #pragma unroll
    for (int r = 0; r < 8; r++) {
      Dl[i0 + r][bq] = Db[r];
      Sl[i0 + r][bq] = Sb[r];
    }
  }
  __syncthreads();
  float ur[8], ui[8], vr[8], vi[8];
  #pragma unroll
  for (int r = 0; r < 8; r++) { ur[r] = 0.f; ui[r] = 0.f; vr[r] = 0.f; vi[r] = 0.f; }
  const float2* wa = WA + (size_t)m * CKD * CKD + o;
  const float2* wb = WB + (size_t)m * CKD * CKD + o;
  const float2* wc = WC + (size_t)m * CKD * CKD + o;
  #pragma unroll 4
  for (int i = 0; i < CKD; i++) {
    float2 a  = wa[(size_t)i * CKD];
    float2 bw = wb[(size_t)i * CKD];
    float2 cw = wc[(size_t)i * CKD];
    float2 dv[8], sv[8];
    #pragma unroll
    for (int r = 0; r < 4; r++) {
      *(float4*)&dv[r*2] = *(const float4*)&Dl[i][(bh << 3) + r*2];
      *(float4*)&sv[r*2] = *(const float4*)&Sl[i][(bh << 3) + r*2];
    }
    #pragma unroll
    for (int r = 0; r < 8; r++) {
      float2 d = dv[r], s = sv[r];
      ur[r] = fmaf(d.x, a.x, ur[r]);  ur[r] = fmaf(-d.y, a.y, ur[r]);
      ur[r] = fmaf(s.x, bw.x, ur[r]); ur[r] = fmaf(-s.y, bw.y, ur[r]);
      ui[r] = fmaf(d.x, a.y, ui[r]);  ui[r] = fmaf(d.y, a.x, ui[r]);
      ui[r] = fmaf(s.x, bw.y, ui[r]); ui[r] = fmaf(s.y, bw.x, ui[r]);
      vr[r] = fmaf(d.x, cw.x, vr[r]); vr[r] = fmaf(-d.y, cw.y, vr[r]);
      vi[r] = fmaf(d.x, cw.y, vi[r]); vi[r] = fmaf(d.y, cw.x, vi[r]);
    }
  }
  #pragma unroll
  for (int r = 0; r < 8; r++) {
    int bq = (bh << 3) + r;
    size_t ob = ((size_t)bq * l + m) * CKD + o;
    u16 h; float xv;
    xv = ur[r]; h = f2bh(xv); Ub[ob] = h;              Ub[(size_t)ps + ob] = f2bh(xv - bh2f(h));
    xv = ui[r]; h = f2bh(xv); Ub[2*(size_t)ps + ob] = h; Ub[3*(size_t)ps + ob] = f2bh(xv - bh2f(h));
    xv = vr[r]; h = f2bh(xv); Ub[4*(size_t)ps + ob] = h; Ub[5*(size_t)ps + ob] = f2bh(xv - bh2f(h));
    xv = vi[r]; h = f2bh(xv); Ub[6*(size_t)ps + ob] = h; Ub[7*(size_t)ps + ob] = f2bh(xv - bh2f(h));
  }
}

// transpose G planes [b][m][o] -> [b][o][m]; grid (NLEV*BB, 8 planes)
__global__ void gt_k(const u16* __restrict__ in, u16* __restrict__ outp,
                     long long ps, MixTab2 mt) {
  __shared__ u16 T[128][136];
  int bx = blockIdx.x;
  int lev = bx >> 4, b = bx & 15;
  int p = blockIdx.y;
  int l = mt.l[lev];
  const u16* ip = in + (size_t)p * ps + mt.off[lev];
  u16* op = outp + (size_t)p * ps + mt.off[lev];
  int tid = threadIdx.x;
  int o8 = (tid & 15) << 3;
  for (int mm = tid >> 4; mm < l; mm += 16) {
    ushort8 v = *(const ushort8*)(ip + ((size_t)b * l + mm) * CKD + o8);
    #pragma unroll
    for (int e = 0; e < 8; e++) T[o8 + e][mm] = v[e];
  }
  __syncthreads();
  bool fast = ((l & 7) == 0);
  int m8 = (tid & 15) << 3;
  for (int o = tid >> 4; o < CKD; o += 16) {
    if (m8 < l) {
      u16* dst = op + ((size_t)b * CKD + o) * l + m8;
      if (fast && m8 + 8 <= l) {
        ushort8 v;
        #pragma unroll
        for (int e = 0; e < 8; e++) v[e] = T[o][m8 + e];
        *(ushort8*)dst = v;
      } else {
        for (int e = 0; m8 + e < l; e++) dst[e] = T[o][m8 + e];
      }
    }
  }
}

// ---- MFMA inverse DFT (split-bf16; LDS-free, direct global frag loads) ----
// y[b,j,o] = (2*sum_m(Gr*cos + Gi*(-sin)) - G0.re - nyq*(-1)^j*Gl.re)/n
// block 256 = 4 waves; tile 64j x 128o; wave = 32j x 64o; K = m chunks of 32
// grid: x = ceil(n/64), y = b, z = {U->ud, V->us}
__global__ void __launch_bounds__(256)
inv_mfma_k(const u16* __restrict__ GU, const u16* __restrict__ GV, long long ps,
           const u16* __restrict__ tch, const u16* __restrict__ tcl,
           const u16* __restrict__ tsh, const u16* __restrict__ tsl,  // sin planes pre-negated
           float* __restrict__ ud, float* __restrict__ us,
           int n, int l, int nyq) {
  int z = blockIdx.z;
  const u16* __restrict__ G = z ? GV : GU;
  float* __restrict__ out = z ? us : ud;
  int b = blockIdx.y;
  int j0 = blockIdx.x << 6;
  int t = threadIdx.x, ln = t & 63, w = t >> 6;
  int wj = (w >> 1) << 5;
  int wo = (w & 1) << 6;
  int lr = ln & 15, kq = ln >> 4;
  bool fast = ((l & 7) == 0);
  f32x4 acc[2][4];
  #pragma unroll
  for (int a = 0; a < 2; a++)
    #pragma unroll
    for (int d = 0; d < 4; d++) acc[a][d] = (f32x4){0.f,0.f,0.f,0.f};
  int nch = (l + 31) >> 5;
  for (int mc = 0; mc < nch; mc++) {
    int ac = (mc << 5) + (kq << 3);
    int rem = l - ac;
    // B frags: G[o][m], 4 planes x 4 o-frags
    bf16x8 Brh[4], Brl[4], Bih[4], Bil[4];
    #pragma unroll
    for (int fi = 0; fi < 4; fi++) {
      int br = wo + (fi << 4) + lr;
      size_t gb = ((size_t)b * CKD + br) * l + ac;
      Brh[fi] = ld8t(G + gb, rem, fast);
      Brl[fi] = ld8t(G + (size_t)ps + gb, rem, fast);
      Bih[fi] = ld8t(G + 2*(size_t)ps + gb, rem, fast);
      Bil[fi] = ld8t(G + 3*(size_t)ps + gb, rem, fast);
    }
    #pragma unroll
    for (int fm = 0; fm < 2; fm++) {
      int jr = j0 + wj + (fm << 4) + lr;
      bf16x8 Ach, Acl, Ash, Asl;
      if (jr < n) {
        size_t ab = (size_t)jr * l + ac;
        Ach = ld8t(tch + ab, rem, fast);
        Acl = ld8t(tcl + ab, rem, fast);
        Ash = ld8t(tsh + ab, rem, fast);
        Asl = ld8t(tsl + ab, rem, fast);
      } else {
        Ach = (bf16x8){0,0,0,0,0,0,0,0}; Acl = Ach; Ash = Ach; Asl = Ach;
      }
      #pragma unroll
      for (int fi = 0; fi < 4; fi++) {
        acc[fm][fi] = __builtin_amdgcn_mfma_f32_16x16x32_bf16(Ach, Brh[fi], acc[fm][fi], 0, 0, 0);
        acc[fm][fi] = __builtin_amdgcn_mfma_f32_16x16x32_bf16(Ach, Brl[fi], acc[fm][fi], 0, 0, 0);
        acc[fm][fi] = __builtin_amdgcn_mfma_f32_16x16x32_bf16(Acl, Brh[fi], acc[fm][fi], 0, 0, 0);
        acc[fm][fi] = __builtin_amdgcn_mfma_f32_16x16x32_bf16(Ash, Bih[fi], acc[fm][fi], 0, 0, 0);
        acc[fm][fi] = __builtin_amdgcn_mfma_f32_16x16x32_bf16(Ash, Bil[fi], acc[fm][fi], 0, 0, 0);
        acc[fm][fi] = __builtin_amdgcn_mfma_f32_16x16x32_bf16(Asl, Bih[fi], acc[fm][fi], 0, 0, 0);
      }
    }
  }
  float invn = 1.f / (float)n;
  #pragma unroll
  for (int fi = 0; fi < 4; fi++) {
    int o = wo + (fi << 4) + lr;
    size_t gb = ((size_t)b * CKD + o) * l;
    float g0 = bh2f(G[gb]) + bh2f(G[(size_t)ps + gb]);
    float gn = nyq ? (bh2f(G[gb + l - 1]) + bh2f(G[(size_t)ps + gb + l - 1])) : 0.f;
    #pragma unroll
    for (int fm = 0; fm < 2; fm++) {
      int jb = j0 + wj + (fm << 4) + (kq << 2);
      #pragma unroll
      for (int rg = 0; rg < 4; rg++) {
        int j = jb + rg;
        if (j < n) {
          float sgn = (j & 1) ? -1.f : 1.f;
          out[((size_t)b * n + j) * CKD + o] = (2.f * acc[fm][fi][rg] - g0 - sgn * gn) * invn;
        }
      }
    }
  }
}

// coarsest map: y = x @ T0_w^T + T0_b
__global__ void t0_k(const float* __restrict__ xin, const float* __restrict__ w,
                     const float* __restrict__ bv, float* __restrict__ xout) {
  int idx = blockIdx.x * blockDim.x + threadIdx.x;
  if (idx >= BB * CC * KK) return;
  int k = idx & 3;
  int bc = idx >> 2;
  float a = bv[k];
  #pragma unroll
  for (int kp = 0; kp < 4; kp++) a = fmaf(xin[bc*4 + kp], w[k*4 + kp], a);
  xout[idx] = a;
}

__global__ void recon_k(const float* __restrict__ xin, const float* __restrict__ usl,
                        const float* __restrict__ udl,
                        const float* __restrict__ rce, const float* __restrict__ rco,
                        float* __restrict__ xout, int nh) {
  int idx = blockIdx.x * blockDim.x + threadIdx.x;
  if (idx >= BB * nh * CC) return;
  int c = idx & (CC - 1);
  int t = idx / CC;
  int j = t % nh;
  int b = t / nh;
  size_t ib = (((size_t)b * nh + j) * CC + c) * KK;
  float4 xv = *(const float4*)(xin + ib);
  float4 uv = *(const float4*)(usl + ib);
  float4 dv = *(const float4*)(udl + ib);
  float xx[8] = {xv.x+uv.x, xv.y+uv.y, xv.z+uv.z, xv.w+uv.w, dv.x, dv.y, dv.z, dv.w};
  float ev[4] = {0.f,0.f,0.f,0.f}, ov[4] = {0.f,0.f,0.f,0.f};
  #pragma unroll
  for (int p = 0; p < 8; p++) {
    float v = xx[p];
    #pragma unroll
    for (int k = 0; k < 4; k++) {
      ev[k] = fmaf(v, rce[p*4+k], ev[k]);
      ov[k] = fmaf(v, rco[p*4+k], ov[k]);
    }
  }
  size_t ob = (((size_t)b * (2*nh) + 2*j) * CC + c) * KK;
  *(float4*)(xout + ob) = make_float4(ev[0], ev[1], ev[2], ev[3]);
  *(float4*)(xout + ob + CC*KK) = make_float4(ov[0], ov[1], ov[2], ov[3]);
}

extern "C" void kernel_launch(void* const* d_in, const int* in_sizes, int n_in,
                              void* d_out, int out_size, void* d_ws, size_t ws_size,
                              hipStream_t stream) {
  const float* x   = (const float*)d_in[0];
  const float* wAr = (const float*)d_in[1];
  const float* wAi = (const float*)d_in[2];
  const float* wBr = (const float*)d_in[3];
  const float* wBi = (const float*)d_in[4];
  const float* wCr = (const float*)d_in[5];
  const float* wCi = (const float*)d_in[6];
  const float *ecs, *ecd, *rce, *rco, *t0w, *t0b;
  if (in_sizes[7] == 16) {
    t0w = (const float*)d_in[7];  t0b = (const float*)d_in[8];
    ecs = (const float*)d_in[9];  ecd = (const float*)d_in[10];
    rce = (const float*)d_in[11]; rco = (const float*)d_in[12];
  } else {
    ecs = (const float*)d_in[7];  ecd = (const float*)d_in[8];
    rce = (const float*)d_in[9];  rco = (const float*)d_in[10];
    t0w = (const float*)d_in[11]; t0b = (const float*)d_in[12];
  }

  int nh[NLEV], lv[NLEV];
  size_t twoff[NLEV], spoff[NLEV];
  size_t tacc = 0, spacc = 0;
  for (int q = 0; q < NLEV; q++) {
    nh[q] = NN >> (q + 1);
    int li = nh[q] / 2 + 1;
    lv[q] = li < AL ? li : AL;
    twoff[q] = tacc; tacc += (size_t)nh[q] * lv[q];
    spoff[q] = spacc; spacc += (size_t)BB * CKD * lv[q];
  }

  float* ws = (float*)d_ws;
  const size_t XS = (size_t)BB * (NN/2) * CKD;     // 8,388,608 floats
  float*  xb0  = ws;                               // XS floats
  float*  xb1  = xb0 + XS;                         // XS/2 floats (recon even-q outputs fit EXACTLY)
  float2* Dall = (float2*)(xb1 + XS / 2);          // spacc float2, fwd spectra [b][m][i]; later Gt8
  float2* Sall = Dall + spacc;
  float2* Uall = Sall + spacc;                     // 8 u16 planes (mix out) / fwd scrD
  float2* Vall = Uall + spacc;
  float*  udT  = (float*)(Vall + spacc);           // XS floats: fwd dh/dl; Wt; recon ud
  float*  usT  = udT + XS;                         // XS floats: fwd sh/sl; recon us; t0buf tail
  // inverse twiddle planes [j][m] (sin negated), 4 x tacc u16
  u16* tjch = (u16*)(usT + XS);
  u16* tjcl = tjch + tacc;
  u16* tjsh = tjcl + tacc;
  u16* tjsl = tjsh + tacc;
  // forward twiddle planes [m][j], 4 x tacc u16
  u16* twCh = tjsl + tacc;
  u16* twCl = twCh + tacc;
  u16* twSh = twCl + tacc;
  u16* twSl = twSh + tacc;
  // bf16 source planes: [b][CKD][n], level-0 sized
  u16* dhp = (u16*)udT;
  u16* dlp = dhp + (size_t)BB * CKD * (NN/2);
  u16* shp = (u16*)usT;
  u16* slp = shp + (size_t)BB * CKD * (NN/2);
  float2* scrD = Uall;                             // fwd K-split D partials
  float2* WtA = (float2*)udT;                      // transposed weights (mix time)
  float2* WtB = WtA + (size_t)CKD * CKD * AL;
  float2* WtC = WtB + (size_t)CKD * CKD * AL;
  u16* Up8 = (u16*)Uall;                           // mix output: 8 planes [b][m][o]
  u16* Gt8 = (u16*)Dall;                           // transposed G: 8 planes [b][o][m] — must survive to q=0
  float* t0buf = usT + XS - 4096;                  // 2048 floats; dead tail of usT (Wt ends at usT+4.2M;
                                                   // inv q=12 writes only usT[0:2048))

  LevTab lt;
  for (int q = 0; q < NLEV; q++) { lt.off[q] = (int)twoff[q]; lt.n[q] = nh[q]; lt.l[q] = lv[q]; }
  lt.total = (int)tacc;
  twiddle_fill_k<<<dim3((unsigned)((tacc + 255) / 256)), 256, 0, stream>>>(
      tjch, tjcl, tjsh, tjsl, twCh, twCl, twSh, twSl, lt);

  // ---------- decompose(+transpose/convert) + MFMA forward DFT ----------
  const float* cur = x;
  float* nxt = xb0;
  for (int q = 0; q < NLEV; q++) {
    int n2 = nh[q], l = lv[q];
    decomp_t_k<<<dim3((n2 + 63) / 64, BB), 256, 0, stream>>>(cur, nxt, dhp, dlp, shp, slp,
                                                             ecs, ecd, n2);
    int P = (n2 >= 512) ? 8 : ((n2 >= 64) ? n2 / 64 : 1);
    int chunk = ((n2 + P - 1) / P + 31) & ~31;
    int mtiles = (l + 63) / 64;
    float* curbuf = (q == 0) ? xb1 : ((q & 1) ? xb0 : xb1);
    float2* Dp = (P > 1) ? scrD : (Dall + spoff[q]);
    float2* Sp = (P > 1) ? (float2*)curbuf : (Sall + spoff[q]);
    fwd_mfma_k<<<dim3(mtiles, BB, 2 * P), 256, 0, stream>>>(
        dhp, dlp, shp, slp,
        twCh + twoff[q], twCl + twoff[q], twSh + twoff[q], twSl + twoff[q],
        Dp, Sp, n2, l, P, chunk);
    if (P > 1) {
      int cnt4 = (BB * CKD * l) / 2;
      reduce_k<<<dim3((2 * cnt4 + 255) / 256), 256, 0, stream>>>(
          (float4*)(Dall + spoff[q]), (float4*)(Sall + spoff[q]),
          (const float4*)scrD, (const float4*)Sp, cnt4, P);
    }
    cur = nxt;
    nxt = (nxt == xb0) ? xb1 : xb0;
  }

  // ---------- transpose weights into [m][i][o] float2 ----------
  wtr_k<<<dim3(CKD, 4, 3), 256, 0, stream>>>(wAr, wAi, wBr, wBi, wCr, wCi, WtA, WtB, WtC);

  // ---------- batched per-(lev,m) complex GEMM mode-mix ----------
  MixTab2 mt;
  int mc = 0;
  for (int q = 0; q < NLEV; q++) {
    mt.off[q] = (long long)spoff[q];
    mt.l[q] = lv[q];
    mt.mcum[q] = mc;
    mc += lv[q];
  }
  mix2_k<<<dim3((unsigned)mc), 256, 0, stream>>>(Dall, Sall, WtA, WtB, WtC,
                                                 Up8, (long long)spacc, mt);

  // ---------- transpose G planes [b][m][o] -> [b][o][m] (Dall/Sall dead post-mix) ----------
  gt_k<<<dim3(NLEV * BB, 8), 256, 0, stream>>>(Up8, Gt8, (long long)spacc, mt);

  // ---------- coarsest linear map (to usT-tail scratch; xb0/xb1 reserved for recon) ----------
  t0_k<<<dim3((BB * CC * KK + 255) / 256), 256, 0, stream>>>(cur, t0w, t0b, t0buf);

  // ---------- reconstruct (MFMA inverse DFT per level) ----------
  // outp: odd q -> xb0 (XS; q=1 output = XS exact), even q -> xb1 (XS/2; q=2 output = XS/2 exact,
  // ends exactly at Dall => Gt8 never clobbered). rcur != outp at every step.
  const float* rcur = t0buf;
  for (int q = NLEV - 1; q >= 0; q--) {
    int n2 = nh[q], l = lv[q];
    int nyq = (((n2 & 1) == 0) && (l == n2 / 2 + 1)) ? 1 : 0;
    inv_mfma_k<<<dim3((n2 + 63) / 64, BB, 2), 256, 0, stream>>>(
        Gt8 + spoff[q], Gt8 + 4 * spacc + spoff[q], (long long)spacc,
        tjch + twoff[q], tjcl + twoff[q], tjsh + twoff[q], tjsl + twoff[q],
        udT, usT, n2, l, nyq);
    float* outp = (q == 0) ? (float*)d_out : ((q & 1) ? xb0 : xb1);
    int tot = BB * n2 * CC;
    recon_k<<<dim3((tot + 255) / 256), 256, 0, stream>>>(rcur, usT, udT,
                                                         rce, rco, outp, n2);
    rcur = outp;
  }
}

// Round 8
// 964.639 us; speedup vs baseline: 1.2189x; 1.2189x over previous
//
#include <hip/hip_runtime.h>

#define BB 16
#define CC 32
#define KK 4
#define CKD 128     // C*K
#define NN 8192
#define NLEV 13
#define AL 128      // ALPHA (weight mode-axis storage stride)

typedef unsigned short u16;
typedef __attribute__((ext_vector_type(8))) short bf16x8;
typedef __attribute__((ext_vector_type(8))) unsigned short ushort8;
typedef __attribute__((ext_vector_type(4))) float f32x4;

struct LevTab { int off[NLEV]; int n[NLEV]; int l[NLEV]; int total; };
struct MixTab2 { long long off[NLEV]; int l[NLEV]; int mcum[NLEV]; };

__device__ __forceinline__ u16 f2bh(float x) {
  union { float f; unsigned u; } v; v.f = x;
  unsigned r = (v.u + 0x7fffu + ((v.u >> 16) & 1u)) >> 16;
  return (u16)r;
}
__device__ __forceinline__ float bh2f(u16 h) {
  union { unsigned u; float f; } v; v.u = ((unsigned)h) << 16; return v.f;
}

// inverse A planes [j][m] (sin NEGATED) + forward planes [m][j] (sin positive)
__global__ void twiddle_fill_k(u16* __restrict__ tjch, u16* __restrict__ tjcl,
                               u16* __restrict__ tjsh, u16* __restrict__ tjsl,
                               u16* __restrict__ tch, u16* __restrict__ tcl,
                               u16* __restrict__ tsh, u16* __restrict__ tsl, LevTab t) {
  int idx = blockIdx.x * blockDim.x + threadIdx.x;
  if (idx >= t.total) return;
  int lev = 0;
  for (int q = 1; q < NLEV; q++) lev = (idx >= t.off[q]) ? q : lev;
  int r = idx - t.off[lev];
  int n = t.n[lev], l = t.l[lev];
  int j = r / l, m = r - j * l;
  long long pp = ((long long)j * (long long)m) % n;
  float ang = (float)((double)pp * (6.283185307179586476925286766559 / (double)n));
  float s, c;
  sincosf(ang, &s, &c);
  // inverse planes, [j][m] = contiguous at idx
  size_t oj = (size_t)idx;
  u16 h = f2bh(c); tjch[oj] = h; tjcl[oj] = f2bh(c - bh2f(h));
  float ns = -s;
  h = f2bh(ns); tjsh[oj] = h; tjsl[oj] = f2bh(ns - bh2f(h));
  // forward planes, [m][j]
  size_t om = (size_t)t.off[lev] + (size_t)m * n + j;
  h = f2bh(c); tch[om] = h; tcl[om] = f2bh(c - bh2f(h));
  h = f2bh(s); tsh[om] = h; tsl[om] = f2bh(s - bh2f(h));
}

// fused decompose + transpose/convert:
// x:(B,2nh,CKD) fp32 -> s:(B,nh,CKD) fp32 (next level input)
//                    -> dh/dl/sh/sl: (B,CKD,nh) bf16 split planes (MFMA operands)
__global__ void decomp_t_k(const float* __restrict__ xin, float* __restrict__ sout,
                           u16* __restrict__ dh, u16* __restrict__ dl,
                           u16* __restrict__ sh, u16* __restrict__ sl,
                           const float* __restrict__ ecs, const float* __restrict__ ecd,
                           int nh) {
  int b = blockIdx.y;
  int j0 = blockIdx.x << 6;
  int t = threadIdx.x;
  int c = t & 31, j8 = t >> 5;
  int jbase = j0 + (j8 << 3);
  float s8[4][8], d8[4][8];
  #pragma unroll
  for (int jj = 0; jj < 8; jj++) {
    int j = jbase + jj;
    float sv[4] = {0.f,0.f,0.f,0.f}, dv[4] = {0.f,0.f,0.f,0.f};
    if (j < nh) {
      size_t ib = (((size_t)b * 2 * nh + 2 * j) * CC + c) * KK;
      float4 xe = *(const float4*)(xin + ib);
      float4 xo = *(const float4*)(xin + ib + CC * KK);
      float xa[8] = {xe.x, xe.y, xe.z, xe.w, xo.x, xo.y, xo.z, xo.w};
      #pragma unroll
      for (int p = 0; p < 8; p++) {
        float v = xa[p];
        #pragma unroll
        for (int k = 0; k < 4; k++) {
          sv[k] = fmaf(v, ecs[p*4+k], sv[k]);
          dv[k] = fmaf(v, ecd[p*4+k], dv[k]);
        }
      }
      size_t ob = (((size_t)b * nh + j) * CC + c) * KK;
      *(float4*)(sout + ob) = make_float4(sv[0], sv[1], sv[2], sv[3]);
    }
    #pragma unroll
    for (int k = 0; k < 4; k++) { s8[k][jj] = sv[k]; d8[k][jj] = dv[k]; }
  }
  if (jbase < nh) {
    bool full = (jbase + 8 <= nh);
    #pragma unroll
    for (int k = 0; k < 4; k++) {
      int i = (c << 2) + k;
      size_t rb = ((size_t)b * CKD + i) * nh + jbase;
      ushort8 vh, vl, wh, wl;
      #pragma unroll
      for (int jj = 0; jj < 8; jj++) {
        float dvv = d8[k][jj];
        u16 h = f2bh(dvv); vh[jj] = h; vl[jj] = f2bh(dvv - bh2f(h));
        float svv = s8[k][jj];
        h = f2bh(svv); wh[jj] = h; wl[jj] = f2bh(svv - bh2f(h));
      }
      if (full) {
        *(ushort8*)(dh + rb) = vh; *(ushort8*)(dl + rb) = vl;
        *(ushort8*)(sh + rb) = wh; *(ushort8*)(sl + rb) = wl;
      } else {
        int lim = nh - jbase;
        for (int jj = 0; jj < lim; jj++) {
          dh[rb+jj] = vh[jj]; dl[rb+jj] = vl[jj];
          sh[rb+jj] = wh[jj]; sl[rb+jj] = wl[jj];
        }
      }
    }
  }
}

// ---- MFMA forward DFT (split-bf16, 3 mfma per product) ----
__global__ void __launch_bounds__(256)
fwd_mfma_k(const u16* __restrict__ dhp, const u16* __restrict__ dlp,
           const u16* __restrict__ shp, const u16* __restrict__ slp,
           const u16* __restrict__ tch, const u16* __restrict__ tcl,
           const u16* __restrict__ tsh, const u16* __restrict__ tsl,
           float2* __restrict__ Dp, float2* __restrict__ Sp,
           int n, int l, int P, int chunk) {
  __shared__ u16 Ts[4][64][40];    // cos_hi, cos_lo, sin_hi, sin_lo  [m][j]
  __shared__ u16 Vs[2][128][40];   // v_hi, v_lo                      [i][j]
  int zz = blockIdx.z;
  int srcs = (zz >= P) ? 1 : 0;
  int ks = zz - srcs * P;
  int b = blockIdx.y;
  int m0 = blockIdx.x << 6;
  const u16* vhp = srcs ? shp : dhp;
  const u16* vlp = srcs ? slp : dlp;
  float2* __restrict__ dst = (srcs ? Sp : Dp) + (size_t)ks * ((size_t)BB * CKD * l);
  int kstart = ks * chunk;
  int kcnt = n - kstart; if (kcnt > chunk) kcnt = chunk; if (kcnt < 0) kcnt = 0;
  int kmax = kstart + kcnt;
  int t = threadIdx.x, ln = t & 63, w = t >> 6;
  int wm = (w >> 1) << 5, wi = (w & 1) << 6;
  f32x4 accr[2][4], acci[2][4];
  #pragma unroll
  for (int a = 0; a < 2; a++)
    #pragma unroll
    for (int d = 0; d < 4; d++) {
      accr[a][d] = (f32x4){0.f,0.f,0.f,0.f};
      acci[a][d] = (f32x4){0.f,0.f,0.f,0.f};
    }
  const u16* tp0 = tch; const u16* tp1 = tcl; const u16* tp2 = tsh; const u16* tp3 = tsl;

  for (int js = 0; js < kcnt; js += 32) {
    #pragma unroll
    for (int it = 0; it < 4; it++) {     // stage T: 4 planes x 64 rows x 4 chunks
      int idx = t + (it << 8);
      int p = idx >> 8, r = (idx >> 2) & 63, jc = idx & 3;
      int jg = kstart + js + (jc << 3);
      ushort8 v = {0,0,0,0,0,0,0,0};
      int mrow = m0 + r;
      if (mrow < l && jg < kmax) {
        const u16* sp = (p == 0 ? tp0 : p == 1 ? tp1 : p == 2 ? tp2 : tp3)
                        + (size_t)mrow * n + jg;
        if (jg + 8 <= kmax) v = *(const ushort8*)sp;
        else { for (int e = 0; e < 8; e++) if (jg + e < kmax) v[e] = sp[e]; }
      }
      *(ushort8*)&Ts[p][r][jc << 3] = v;
    }
    #pragma unroll
    for (int it = 0; it < 4; it++) {     // stage V: 2 planes x 128 rows x 4 chunks
      int idx = t + (it << 8);
      int p = idx >> 9, r = (idx >> 2) & 127, jc = idx & 3;
      int jg = kstart + js + (jc << 3);
      ushort8 v = {0,0,0,0,0,0,0,0};
      if (jg < kmax) {
        const u16* bp = (p ? vlp : vhp) + ((size_t)b * CKD + r) * n + jg;
        if (jg + 8 <= kmax) v = *(const ushort8*)bp;
        else { for (int e = 0; e < 8; e++) if (jg + e < kmax) v[e] = bp[e]; }
      }
      *(ushort8*)&Vs[p][r][jc << 3] = v;
    }
    __syncthreads();
    int ac = (ln >> 4) << 3;
    #pragma unroll
    for (int fm = 0; fm < 2; fm++) {
      int ar = wm + (fm << 4) + (ln & 15);
      bf16x8 ach = *(const bf16x8*)&Ts[0][ar][ac];
      bf16x8 acl = *(const bf16x8*)&Ts[1][ar][ac];
      bf16x8 ash = *(const bf16x8*)&Ts[2][ar][ac];
      bf16x8 asl = *(const bf16x8*)&Ts[3][ar][ac];
      #pragma unroll
      for (int fi = 0; fi < 4; fi++) {
        int br = wi + (fi << 4) + (ln & 15);
        bf16x8 bh = *(const bf16x8*)&Vs[0][br][ac];
        bf16x8 bl = *(const bf16x8*)&Vs[1][br][ac];
        accr[fm][fi] = __builtin_amdgcn_mfma_f32_16x16x32_bf16(ach, bh, accr[fm][fi], 0, 0, 0);
        accr[fm][fi] = __builtin_amdgcn_mfma_f32_16x16x32_bf16(ach, bl, accr[fm][fi], 0, 0, 0);
        accr[fm][fi] = __builtin_amdgcn_mfma_f32_16x16x32_bf16(acl, bh, accr[fm][fi], 0, 0, 0);
        acci[fm][fi] = __builtin_amdgcn_mfma_f32_16x16x32_bf16(ash, bh, acci[fm][fi], 0, 0, 0);
        acci[fm][fi] = __builtin_amdgcn_mfma_f32_16x16x32_bf16(ash, bl, acci[fm][fi], 0, 0, 0);
        acci[fm][fi] = __builtin_amdgcn_mfma_f32_16x16x32_bf16(asl, bh, acci[fm][fi], 0, 0, 0);
      }
    }
    __syncthreads();
  }
  #pragma unroll
  for (int fm = 0; fm < 2; fm++)
    #pragma unroll
    for (int fi = 0; fi < 4; fi++) {
      int i = wi + (fi << 4) + (ln & 15);
      int mb = m0 + wm + (fm << 4) + ((ln >> 4) << 2);
      #pragma unroll
      for (int rg = 0; rg < 4; rg++) {
        int m = mb + rg;
        if (m < l)
          dst[((size_t)b * l + m) * CKD + i] = make_float2(accr[fm][fi][rg], -acci[fm][fi][rg]);
      }
    }
}

// sum P partial spectra (scratch) into compact Dall/Sall slots
__global__ void reduce_k(float4* __restrict__ dD, float4* __restrict__ dS,
                         const float4* __restrict__ pD, const float4* __restrict__ pS,
                         int cnt4, int P) {
  int idx = blockIdx.x * blockDim.x + threadIdx.x;
  if (idx >= 2 * cnt4) return;
  const float4* src = (idx < cnt4) ? pD : pS;
  float4* dst = (idx < cnt4) ? dD : dS;
  int e = (idx < cnt4) ? idx : idx - cnt4;
  float4 a = src[e];
  for (int p = 1; p < P; p++) {
    float4 v = src[(size_t)p * cnt4 + e];
    a.x += v.x; a.y += v.y; a.z += v.z; a.w += v.w;
  }
  dst[e] = a;
}

// weight transpose: W[i][o][m] (re,im separate) -> Wt[m][i][o] interleaved float2
__global__ void wtr_k(const float* __restrict__ Ar, const float* __restrict__ Ai,
                      const float* __restrict__ Br, const float* __restrict__ Bi,
                      const float* __restrict__ Cr, const float* __restrict__ Ci,
                      float2* __restrict__ WtA, float2* __restrict__ WtB,
                      float2* __restrict__ WtC) {
  __shared__ float2 Ts[32][130];
  int i = blockIdx.x;
  int o0 = blockIdx.y << 5;
  int z = blockIdx.z;
  const float* Wr = (z == 0) ? Ar : ((z == 1) ? Br : Cr);
  const float* Wi = (z == 0) ? Ai : ((z == 1) ? Bi : Ci);
  float2* Wt = (z == 0) ? WtA : ((z == 1) ? WtB : WtC);
  int tid = threadIdx.x;
  {
    int o = tid >> 3, m0 = (tid & 7) << 4;
    const float* rp = Wr + ((size_t)i * CKD + o0 + o) * AL + m0;
    const float* ip = Wi + ((size_t)i * CKD + o0 + o) * AL + m0;
    #pragma unroll
    for (int r = 0; r < 4; r++) {
      float4 vr = *(const float4*)(rp + r * 4);
      float4 vi = *(const float4*)(ip + r * 4);
      Ts[o][m0 + r*4 + 0] = make_float2(vr.x, vi.x);
      Ts[o][m0 + r*4 + 1] = make_float2(vr.y, vi.y);
      Ts[o][m0 + r*4 + 2] = make_float2(vr.z, vi.z);
      Ts[o][m0 + r*4 + 3] = make_float2(vr.w, vi.w);
    }
  }
  __syncthreads();
  {
    int m = tid >> 1, oh = (tid & 1) << 4;
    float2* wp = Wt + ((size_t)m * CKD + i) * CKD + o0 + oh;
    #pragma unroll
    for (int r = 0; r < 16; r += 2) {
      float2 e0 = Ts[oh + r][m];
      float2 e1 = Ts[oh + r + 1][m];
      *(float4*)(wp + r) = make_float4(e0.x, e0.y, e1.x, e1.y);
    }
  }
}

// batched per-(lev,m) complex GEMM; outputs written as 8 split-bf16 planes [b][m][o]
// plane order: 0..3 = U rh,rl,ih,il ; 4..7 = V rh,rl,ih,il ; plane stride ps
__global__ void __launch_bounds__(256)
mix2_k(const float2* __restrict__ Dall, const float2* __restrict__ Sall,
       const float2* __restrict__ WA, const float2* __restrict__ WB,
       const float2* __restrict__ WC,
       u16* __restrict__ Up8, long long ps, MixTab2 mt) {
  __shared__ __align__(16) float2 Dl[CKD][BB];
  __shared__ __align__(16) float2 Sl[CKD][BB];
  int bx = blockIdx.x;
  int lev = 0;
  #pragma unroll
  for (int q = 1; q < NLEV; q++) lev = (bx >= mt.mcum[q]) ? q : lev;
  int m = bx - mt.mcum[lev];
  int l = mt.l[lev];
  const float2* __restrict__ D = Dall + mt.off[lev];
  const float2* __restrict__ S = Sall + mt.off[lev];
  u16* __restrict__ Ub = Up8 + mt.off[lev];
  int tid = threadIdx.x;
  int o = tid & (CKD - 1), bh = tid >> 7;
  {
    int bq = tid & 15, i0 = (tid >> 4) << 3;
    const float2* Db = D + ((size_t)bq * l + m) * CKD + i0;
    const float2* Sb = S + ((size_t)bq * l + m) * CKD + i0;
    #pragma unroll
    for (int r = 0; r < 8; r++) {
      Dl[i0 + r][bq] = Db[r];
      Sl[i0 + r][bq] = Sb[r];
    }
  }
  __syncthreads();
  float ur[8], ui[8], vr[8], vi[8];
  #pragma unroll
  for (int r = 0; r < 8; r++) { ur[r] = 0.f; ui[r] = 0.f; vr[r] = 0.f; vi[r] = 0.f; }
  const float2* wa = WA + (size_t)m * CKD * CKD + o;
  const float2* wb = WB + (size_t)m * CKD * CKD + o;
  const float2* wc = WC + (size_t)m * CKD * CKD + o;
  #pragma unroll 4
  for (int i = 0; i < CKD; i++) {
    float2 a  = wa[(size_t)i * CKD];
    float2 bw = wb[(size_t)i * CKD];
    float2 cw = wc[(size_t)i * CKD];
    float2 dv[8], sv[8];
    #pragma unroll
    for (int r = 0; r < 4; r++) {
      *(float4*)&dv[r*2] = *(const float4*)&Dl[i][(bh << 3) + r*2];
      *(float4*)&sv[r*2] = *(const float4*)&Sl[i][(bh << 3) + r*2];
    }
    #pragma unroll
    for (int r = 0; r < 8; r++) {
      float2 d = dv[r], s = sv[r];
      ur[r] = fmaf(d.x, a.x, ur[r]);  ur[r] = fmaf(-d.y, a.y, ur[r]);
      ur[r] = fmaf(s.x, bw.x, ur[r]); ur[r] = fmaf(-s.y, bw.y, ur[r]);
      ui[r] = fmaf(d.x, a.y, ui[r]);  ui[r] = fmaf(d.y, a.x, ui[r]);
      ui[r] = fmaf(s.x, bw.y, ui[r]); ui[r] = fmaf(s.y, bw.x, ui[r]);
      vr[r] = fmaf(d.x, cw.x, vr[r]); vr[r] = fmaf(-d.y, cw.y, vr[r]);
      vi[r] = fmaf(d.x, cw.y, vi[r]); vi[r] = fmaf(d.y, cw.x, vi[r]);
    }
  }
  #pragma unroll
  for (int r = 0; r < 8; r++) {
    int bq = (bh << 3) + r;
    size_t ob = ((size_t)bq * l + m) * CKD + o;
    u16 h; float xv;
    xv = ur[r]; h = f2bh(xv); Ub[ob] = h;              Ub[(size_t)ps + ob] = f2bh(xv - bh2f(h));
    xv = ui[r]; h = f2bh(xv); Ub[2*(size_t)ps + ob] = h; Ub[3*(size_t)ps + ob] = f2bh(xv - bh2f(h));
    xv = vr[r]; h = f2bh(xv); Ub[4*(size_t)ps + ob] = h; Ub[5*(size_t)ps + ob] = f2bh(xv - bh2f(h));
    xv = vi[r]; h = f2bh(xv); Ub[6*(size_t)ps + ob] = h; Ub[7*(size_t)ps + ob] = f2bh(xv - bh2f(h));
  }
}

// transpose G planes [b][m][o] -> [b][o][m]; grid (NLEV*BB, 8 planes)
__global__ void gt_k(const u16* __restrict__ in, u16* __restrict__ outp,
                     long long ps, MixTab2 mt) {
  __shared__ u16 T[128][136];
  int bx = blockIdx.x;
  int lev = bx >> 4, b = bx & 15;
  int p = blockIdx.y;
  int l = mt.l[lev];
  const u16* ip = in + (size_t)p * ps + mt.off[lev];
  u16* op = outp + (size_t)p * ps + mt.off[lev];
  int tid = threadIdx.x;
  int o8 = (tid & 15) << 3;
  for (int mm = tid >> 4; mm < l; mm += 16) {
    ushort8 v = *(const ushort8*)(ip + ((size_t)b * l + mm) * CKD + o8);
    #pragma unroll
    for (int e = 0; e < 8; e++) T[o8 + e][mm] = v[e];
  }
  __syncthreads();
  bool fast = ((l & 7) == 0);
  int m8 = (tid & 15) << 3;
  for (int o = tid >> 4; o < CKD; o += 16) {
    if (m8 < l) {
      u16* dst = op + ((size_t)b * CKD + o) * l + m8;
      if (fast && m8 + 8 <= l) {
        ushort8 v;
        #pragma unroll
        for (int e = 0; e < 8; e++) v[e] = T[o][m8 + e];
        *(ushort8*)dst = v;
      } else {
        for (int e = 0; m8 + e < l; e++) dst[e] = T[o][m8 + e];
      }
    }
  }
}

// ---- MFMA inverse DFT v2 (split-bf16, LDS-staged, 2-phase per m-chunk) ----
// y[b,j,o] = (2*sum_m(Gr*cos + Gi*(-sin)) - G0.re - nyq*(-1)^j*Gl.re)/n
// block 256 = 4 waves; tile 64j x 128o; wave = 32j x 64o; K = m chunks of 32.
// Phase 0: A={cos hi,lo}, B={Gr hi,lo}; Phase 1: A={-sin hi,lo}, B={Gi hi,lo}.
// LDS 30 KB -> 5 blocks/CU. grid: x = ceil(n/64), y = b, z = {U->ud, V->us}
__global__ void __launch_bounds__(256)
inv_mfma_k(const u16* __restrict__ GU, const u16* __restrict__ GV, long long ps,
           const u16* __restrict__ tch, const u16* __restrict__ tcl,
           const u16* __restrict__ tsh, const u16* __restrict__ tsl,  // sin planes pre-negated
           float* __restrict__ ud, float* __restrict__ us,
           int n, int l, int nyq) {
  __shared__ u16 Ts[2][64][40];    // A: twiddle [j][m] (hi, lo)
  __shared__ u16 Gs[2][128][40];   // B: G [o][m] (hi, lo)
  int z = blockIdx.z;
  const u16* __restrict__ G = z ? GV : GU;
  float* __restrict__ out = z ? us : ud;
  int b = blockIdx.y;
  int j0 = blockIdx.x << 6;
  int t = threadIdx.x, ln = t & 63, w = t >> 6;
  int wj = (w >> 1) << 5;
  int wo = (w & 1) << 6;
  int lr = ln & 15, kq = ln >> 4;
  f32x4 acc[2][4];
  #pragma unroll
  for (int a = 0; a < 2; a++)
    #pragma unroll
    for (int d = 0; d < 4; d++) acc[a][d] = (f32x4){0.f,0.f,0.f,0.f};
  int nch = (l + 31) >> 5;
  for (int mc = 0; mc < nch; mc++) {
    int ms = mc << 5;
    #pragma unroll
    for (int ph = 0; ph < 2; ph++) {
      const u16* Ah = ph ? tsh : tch;
      const u16* Al = ph ? tsl : tcl;
      const u16* Bh = G + (ph ? 2 * (size_t)ps : 0);
      const u16* Bl = G + (ph ? 3 * (size_t)ps : (size_t)ps);
      #pragma unroll
      for (int it = 0; it < 2; it++) {   // stage A: 2 planes x 64 rows x 4 chunks
        int idx = t + (it << 8);
        int p = idx >> 8, r = (idx >> 2) & 63, jc = idx & 3;
        int jg = j0 + r;
        int mg = ms + (jc << 3);
        ushort8 v = {0,0,0,0,0,0,0,0};
        if (jg < n && mg < l) {
          const u16* sp = (p ? Al : Ah) + (size_t)jg * l + mg;
          if (mg + 8 <= l) v = *(const ushort8*)sp;
          else { for (int e = 0; e < 8; e++) if (mg + e < l) v[e] = sp[e]; }
        }
        *(ushort8*)&Ts[p][r][jc << 3] = v;
      }
      #pragma unroll
      for (int it = 0; it < 4; it++) {   // stage B: 2 planes x 128 rows x 4 chunks
        int idx = t + (it << 8);
        int p = idx >> 9, r = (idx >> 2) & 127, jc = idx & 3;
        int mg = ms + (jc << 3);
        ushort8 v = {0,0,0,0,0,0,0,0};
        if (mg < l) {
          const u16* bp = (p ? Bl : Bh) + ((size_t)b * CKD + r) * l + mg;
          if (mg + 8 <= l) v = *(const ushort8*)bp;
          else { for (int e = 0; e < 8; e++) if (mg + e < l) v[e] = bp[e]; }
        }
        *(ushort8*)&Gs[p][r][jc << 3] = v;
      }
      __syncthreads();
      int ac = kq << 3;
      #pragma unroll
      for (int fm = 0; fm < 2; fm++) {
        int ar = wj + (fm << 4) + lr;
        bf16x8 ah = *(const bf16x8*)&Ts[0][ar][ac];
        bf16x8 al = *(const bf16x8*)&Ts[1][ar][ac];
        #pragma unroll
        for (int fi = 0; fi < 4; fi++) {
          int br = wo + (fi << 4) + lr;
          bf16x8 bh = *(const bf16x8*)&Gs[0][br][ac];
          bf16x8 bl = *(const bf16x8*)&Gs[1][br][ac];
          acc[fm][fi] = __builtin_amdgcn_mfma_f32_16x16x32_bf16(ah, bh, acc[fm][fi], 0, 0, 0);
          acc[fm][fi] = __builtin_amdgcn_mfma_f32_16x16x32_bf16(ah, bl, acc[fm][fi], 0, 0, 0);
          acc[fm][fi] = __builtin_amdgcn_mfma_f32_16x16x32_bf16(al, bh, acc[fm][fi], 0, 0, 0);
        }
      }
      __syncthreads();
    }
  }
  float invn = 1.f / (float)n;
  #pragma unroll
  for (int fi = 0; fi < 4; fi++) {
    int o = wo + (fi << 4) + lr;
    size_t gb = ((size_t)b * CKD + o) * l;
    float g0 = bh2f(G[gb]) + bh2f(G[(size_t)ps + gb]);
    float gn = nyq ? (bh2f(G[gb + l - 1]) + bh2f(G[(size_t)ps + gb + l - 1])) : 0.f;
    #pragma unroll
    for (int fm = 0; fm < 2; fm++) {
      int jb = j0 + wj + (fm << 4) + (kq << 2);
      #pragma unroll
      for (int rg = 0; rg < 4; rg++) {
        int j = jb + rg;
        if (j < n) {
          float sgn = (j & 1) ? -1.f : 1.f;
          out[((size_t)b * n + j) * CKD + o] = (2.f * acc[fm][fi][rg] - g0 - sgn * gn) * invn;
        }
      }
    }
  }
}

// coarsest map: y = x @ T0_w^T + T0_b
__global__ void t0_k(const float* __restrict__ xin, const float* __restrict__ w,
                     const float* __restrict__ bv, float* __restrict__ xout) {
  int idx = blockIdx.x * blockDim.x + threadIdx.x;
  if (idx >= BB * CC * KK) return;
  int k = idx & 3;
  int bc = idx >> 2;
  float a = bv[k];
  #pragma unroll
  for (int kp = 0; kp < 4; kp++) a = fmaf(xin[bc*4 + kp], w[k*4 + kp], a);
  xout[idx] = a;
}

__global__ void recon_k(const float* __restrict__ xin, const float* __restrict__ usl,
                        const float* __restrict__ udl,
                        const float* __restrict__ rce, const float* __restrict__ rco,
                        float* __restrict__ xout, int nh) {
  int idx = blockIdx.x * blockDim.x + threadIdx.x;
  if (idx >= BB * nh * CC) return;
  int c = idx & (CC - 1);
  int t = idx / CC;
  int j = t % nh;
  int b = t / nh;
  size_t ib = (((size_t)b * nh + j) * CC + c) * KK;
  float4 xv = *(const float4*)(xin + ib);
  float4 uv = *(const float4*)(usl + ib);
  float4 dv = *(const float4*)(udl + ib);
  float xx[8] = {xv.x+uv.x, xv.y+uv.y, xv.z+uv.z, xv.w+uv.w, dv.x, dv.y, dv.z, dv.w};
  float ev[4] = {0.f,0.f,0.f,0.f}, ov[4] = {0.f,0.f,0.f,0.f};
  #pragma unroll
  for (int p = 0; p < 8; p++) {
    float v = xx[p];
    #pragma unroll
    for (int k = 0; k < 4; k++) {
      ev[k] = fmaf(v, rce[p*4+k], ev[k]);
      ov[k] = fmaf(v, rco[p*4+k], ov[k]);
    }
  }
  size_t ob = (((size_t)b * (2*nh) + 2*j) * CC + c) * KK;
  *(float4*)(xout + ob) = make_float4(ev[0], ev[1], ev[2], ev[3]);
  *(float4*)(xout + ob + CC*KK) = make_float4(ov[0], ov[1], ov[2], ov[3]);
}

extern "C" void kernel_launch(void* const* d_in, const int* in_sizes, int n_in,
                              void* d_out, int out_size, void* d_ws, size_t ws_size,
                              hipStream_t stream) {
  const float* x   = (const float*)d_in[0];
  const float* wAr = (const float*)d_in[1];
  const float* wAi = (const float*)d_in[2];
  const float* wBr = (const float*)d_in[3];
  const float* wBi = (const float*)d_in[4];
  const float* wCr = (const float*)d_in[5];
  const float* wCi = (const float*)d_in[6];
  const float *ecs, *ecd, *rce, *rco, *t0w, *t0b;
  if (in_sizes[7] == 16) {
    t0w = (const float*)d_in[7];  t0b = (const float*)d_in[8];
    ecs = (const float*)d_in[9];  ecd = (const float*)d_in[10];
    rce = (const float*)d_in[11]; rco = (const float*)d_in[12];
  } else {
    ecs = (const float*)d_in[7];  ecd = (const float*)d_in[8];
    rce = (const float*)d_in[9];  rco = (const float*)d_in[10];
    t0w = (const float*)d_in[11]; t0b = (const float*)d_in[12];
  }

  int nh[NLEV], lv[NLEV];
  size_t twoff[NLEV], spoff[NLEV];
  size_t tacc = 0, spacc = 0;
  for (int q = 0; q < NLEV; q++) {
    nh[q] = NN >> (q + 1);
    int li = nh[q] / 2 + 1;
    lv[q] = li < AL ? li : AL;
    twoff[q] = tacc; tacc += (size_t)nh[q] * lv[q];
    spoff[q] = spacc; spacc += (size_t)BB * CKD * lv[q];
  }

  float* ws = (float*)d_ws;
  const size_t XS = (size_t)BB * (NN/2) * CKD;     // 8,388,608 floats
  float*  xb0  = ws;                               // XS floats
  float*  xb1  = xb0 + XS;                         // XS/2 floats (recon even-q outputs fit EXACTLY)
  float2* Dall = (float2*)(xb1 + XS / 2);          // spacc float2, fwd spectra [b][m][i]; later Gt8
  float2* Sall = Dall + spacc;
  float2* Uall = Sall + spacc;                     // 8 u16 planes (mix out) / fwd scrD
  float2* Vall = Uall + spacc;
  float*  udT  = (float*)(Vall + spacc);           // XS floats: fwd dh/dl; Wt; recon ud
  float*  usT  = udT + XS;                         // XS floats: fwd sh/sl; recon us; t0buf tail
  // inverse twiddle planes [j][m] (sin negated), 4 x tacc u16
  u16* tjch = (u16*)(usT + XS);
  u16* tjcl = tjch + tacc;
  u16* tjsh = tjcl + tacc;
  u16* tjsl = tjsh + tacc;
  // forward twiddle planes [m][j], 4 x tacc u16
  u16* twCh = tjsl + tacc;
  u16* twCl = twCh + tacc;
  u16* twSh = twCl + tacc;
  u16* twSl = twSh + tacc;
  // bf16 source planes: [b][CKD][n], level-0 sized
  u16* dhp = (u16*)udT;
  u16* dlp = dhp + (size_t)BB * CKD * (NN/2);
  u16* shp = (u16*)usT;
  u16* slp = shp + (size_t)BB * CKD * (NN/2);
  float2* scrD = Uall;                             // fwd K-split D partials
  float2* WtA = (float2*)udT;                      // transposed weights (mix time)
  float2* WtB = WtA + (size_t)CKD * CKD * AL;
  float2* WtC = WtB + (size_t)CKD * CKD * AL;
  u16* Up8 = (u16*)Uall;                           // mix output: 8 planes [b][m][o]
  u16* Gt8 = (u16*)Dall;                           // transposed G: 8 planes [b][o][m] — survives to q=0
  float* t0buf = usT + XS - 4096;                  // 2048 floats; dead tail of usT

  LevTab lt;
  for (int q = 0; q < NLEV; q++) { lt.off[q] = (int)twoff[q]; lt.n[q] = nh[q]; lt.l[q] = lv[q]; }
  lt.total = (int)tacc;
  twiddle_fill_k<<<dim3((unsigned)((tacc + 255) / 256)), 256, 0, stream>>>(
      tjch, tjcl, tjsh, tjsl, twCh, twCl, twSh, twSl, lt);

  // ---------- decompose(+transpose/convert) + MFMA forward DFT ----------
  const float* cur = x;
  float* nxt = xb0;
  for (int q = 0; q < NLEV; q++) {
    int n2 = nh[q], l = lv[q];
    decomp_t_k<<<dim3((n2 + 63) / 64, BB), 256, 0, stream>>>(cur, nxt, dhp, dlp, shp, slp,
                                                             ecs, ecd, n2);
    int P = (n2 >= 512) ? 8 : ((n2 >= 64) ? n2 / 64 : 1);
    int chunk = ((n2 + P - 1) / P + 31) & ~31;
    int mtiles = (l + 63) / 64;
    float* curbuf = (q == 0) ? xb1 : ((q & 1) ? xb0 : xb1);
    float2* Dp = (P > 1) ? scrD : (Dall + spoff[q]);
    float2* Sp = (P > 1) ? (float2*)curbuf : (Sall + spoff[q]);
    fwd_mfma_k<<<dim3(mtiles, BB, 2 * P), 256, 0, stream>>>(
        dhp, dlp, shp, slp,
        twCh + twoff[q], twCl + twoff[q], twSh + twoff[q], twSl + twoff[q],
        Dp, Sp, n2, l, P, chunk);
    if (P > 1) {
      int cnt4 = (BB * CKD * l) / 2;
      reduce_k<<<dim3((2 * cnt4 + 255) / 256), 256, 0, stream>>>(
          (float4*)(Dall + spoff[q]), (float4*)(Sall + spoff[q]),
          (const float4*)scrD, (const float4*)Sp, cnt4, P);
    }
    cur = nxt;
    nxt = (nxt == xb0) ? xb1 : xb0;
  }

  // ---------- transpose weights into [m][i][o] float2 ----------
  wtr_k<<<dim3(CKD, 4, 3), 256, 0, stream>>>(wAr, wAi, wBr, wBi, wCr, wCi, WtA, WtB, WtC);

  // ---------- batched per-(lev,m) complex GEMM mode-mix ----------
  MixTab2 mt;
  int mc = 0;
  for (int q = 0; q < NLEV; q++) {
    mt.off[q] = (long long)spoff[q];
    mt.l[q] = lv[q];
    mt.mcum[q] = mc;
    mc += lv[q];
  }
  mix2_k<<<dim3((unsigned)mc), 256, 0, stream>>>(Dall, Sall, WtA, WtB, WtC,
                                                 Up8, (long long)spacc, mt);

  // ---------- transpose G planes [b][m][o] -> [b][o][m] (Dall/Sall dead post-mix) ----------
  gt_k<<<dim3(NLEV * BB, 8), 256, 0, stream>>>(Up8, Gt8, (long long)spacc, mt);

  // ---------- coarsest linear map (to usT-tail scratch; xb0/xb1 reserved for recon) ----------
  t0_k<<<dim3((BB * CC * KK + 255) / 256), 256, 0, stream>>>(cur, t0w, t0b, t0buf);

  // ---------- reconstruct (MFMA inverse DFT per level) ----------
  const float* rcur = t0buf;
  for (int q = NLEV - 1; q >= 0; q--) {
    int n2 = nh[q], l = lv[q];
    int nyq = (((n2 & 1) == 0) && (l == n2 / 2 + 1)) ? 1 : 0;
    inv_mfma_k<<<dim3((n2 + 63) / 64, BB, 2), 256, 0, stream>>>(
        Gt8 + spoff[q], Gt8 + 4 * spacc + spoff[q], (long long)spacc,
        tjch + twoff[q], tjcl + twoff[q], tjsh + twoff[q], tjsl + twoff[q],
        udT, usT, n2, l, nyq);
    float* outp = (q == 0) ? (float*)d_out : ((q & 1) ? xb0 : xb1);
    int tot = BB * n2 * CC;
    recon_k<<<dim3((tot + 255) / 256), 256, 0, stream>>>(rcur, usT, udT,
                                                         rce, rco, outp, n2);
    rcur = outp;
  }
}

// Round 9
// 865.233 us; speedup vs baseline: 1.3589x; 1.1149x over previous
//
#include <hip/hip_runtime.h>

#define BB 16
#define CC 32
#define KK 4
#define CKD 128     // C*K
#define NN 8192
#define NLEV 13
#define AL 128      // ALPHA (weight mode-axis storage stride)
#define PSW ((size_t)CKD * CKD * AL)   // weight plane stride (u16 elems)

typedef unsigned short u16;
typedef __attribute__((ext_vector_type(8))) short bf16x8;
typedef __attribute__((ext_vector_type(8))) unsigned short ushort8;
typedef __attribute__((ext_vector_type(4))) float f32x4;

struct LevTab { int off[NLEV]; int n[NLEV]; int l[NLEV]; int total; };
struct MixTab2 { long long off[NLEV]; int l[NLEV]; int mcum[NLEV]; };

__device__ __forceinline__ u16 f2bh(float x) {
  union { float f; unsigned u; } v; v.f = x;
  unsigned r = (v.u + 0x7fffu + ((v.u >> 16) & 1u)) >> 16;
  return (u16)r;
}
__device__ __forceinline__ float bh2f(u16 h) {
  union { unsigned u; float f; } v; v.u = ((unsigned)h) << 16; return v.f;
}

// inverse A planes [j][m] (sin NEGATED, hi/lo) + forward planes [m][j]
__global__ void twiddle_fill_k(u16* __restrict__ tjch, u16* __restrict__ tjcl,
                               u16* __restrict__ tjsh, u16* __restrict__ tjsl,
                               u16* __restrict__ tch, u16* __restrict__ tcl,
                               u16* __restrict__ tsh, u16* __restrict__ tsl, LevTab t) {
  int idx = blockIdx.x * blockDim.x + threadIdx.x;
  if (idx >= t.total) return;
  int lev = 0;
  for (int q = 1; q < NLEV; q++) lev = (idx >= t.off[q]) ? q : lev;
  int r = idx - t.off[lev];
  int n = t.n[lev], l = t.l[lev];
  int j = r / l, m = r - j * l;
  long long pp = ((long long)j * (long long)m) % n;
  float ang = (float)((double)pp * (6.283185307179586476925286766559 / (double)n));
  float s, c;
  sincosf(ang, &s, &c);
  size_t oj = (size_t)idx;
  u16 h = f2bh(c); tjch[oj] = h; tjcl[oj] = f2bh(c - bh2f(h));
  float ns = -s;
  h = f2bh(ns); tjsh[oj] = h; tjsl[oj] = f2bh(ns - bh2f(h));
  size_t om = (size_t)t.off[lev] + (size_t)m * n + j;
  h = f2bh(c); tch[om] = h; tcl[om] = f2bh(c - bh2f(h));
  h = f2bh(s); tsh[om] = h; tsl[om] = f2bh(s - bh2f(h));
}

// fused decompose + transpose/convert:
// x:(B,2nh,CKD) fp32 -> s:(B,nh,CKD) fp32 (next level input)
//                    -> dh/dl/sh/sl: (B,CKD,nh) bf16 split planes (MFMA operands)
__global__ void decomp_t_k(const float* __restrict__ xin, float* __restrict__ sout,
                           u16* __restrict__ dh, u16* __restrict__ dl,
                           u16* __restrict__ sh, u16* __restrict__ sl,
                           const float* __restrict__ ecs, const float* __restrict__ ecd,
                           int nh) {
  int b = blockIdx.y;
  int j0 = blockIdx.x << 6;
  int t = threadIdx.x;
  int c = t & 31, j8 = t >> 5;
  int jbase = j0 + (j8 << 3);
  float s8[4][8], d8[4][8];
  #pragma unroll
  for (int jj = 0; jj < 8; jj++) {
    int j = jbase + jj;
    float sv[4] = {0.f,0.f,0.f,0.f}, dv[4] = {0.f,0.f,0.f,0.f};
    if (j < nh) {
      size_t ib = (((size_t)b * 2 * nh + 2 * j) * CC + c) * KK;
      float4 xe = *(const float4*)(xin + ib);
      float4 xo = *(const float4*)(xin + ib + CC * KK);
      float xa[8] = {xe.x, xe.y, xe.z, xe.w, xo.x, xo.y, xo.z, xo.w};
      #pragma unroll
      for (int p = 0; p < 8; p++) {
        float v = xa[p];
        #pragma unroll
        for (int k = 0; k < 4; k++) {
          sv[k] = fmaf(v, ecs[p*4+k], sv[k]);
          dv[k] = fmaf(v, ecd[p*4+k], dv[k]);
        }
      }
      size_t ob = (((size_t)b * nh + j) * CC + c) * KK;
      *(float4*)(sout + ob) = make_float4(sv[0], sv[1], sv[2], sv[3]);
    }
    #pragma unroll
    for (int k = 0; k < 4; k++) { s8[k][jj] = sv[k]; d8[k][jj] = dv[k]; }
  }
  if (jbase < nh) {
    bool full = (jbase + 8 <= nh);
    #pragma unroll
    for (int k = 0; k < 4; k++) {
      int i = (c << 2) + k;
      size_t rb = ((size_t)b * CKD + i) * nh + jbase;
      ushort8 vh, vl, wh, wl;
      #pragma unroll
      for (int jj = 0; jj < 8; jj++) {
        float dvv = d8[k][jj];
        u16 h = f2bh(dvv); vh[jj] = h; vl[jj] = f2bh(dvv - bh2f(h));
        float svv = s8[k][jj];
        h = f2bh(svv); wh[jj] = h; wl[jj] = f2bh(svv - bh2f(h));
      }
      if (full) {
        *(ushort8*)(dh + rb) = vh; *(ushort8*)(dl + rb) = vl;
        *(ushort8*)(sh + rb) = wh; *(ushort8*)(sl + rb) = wl;
      } else {
        int lim = nh - jbase;
        for (int jj = 0; jj < lim; jj++) {
          dh[rb+jj] = vh[jj]; dl[rb+jj] = vl[jj];
          sh[rb+jj] = wh[jj]; sl[rb+jj] = wl[jj];
        }
      }
    }
  }
}

// ---- MFMA forward DFT (split-bf16, 3 mfma per product) ----
__global__ void __launch_bounds__(256)
fwd_mfma_k(const u16* __restrict__ dhp, const u16* __restrict__ dlp,
           const u16* __restrict__ shp, const u16* __restrict__ slp,
           const u16* __restrict__ tch, const u16* __restrict__ tcl,
           const u16* __restrict__ tsh, const u16* __restrict__ tsl,
           float2* __restrict__ Dp, float2* __restrict__ Sp,
           int n, int l, int P, int chunk) {
  __shared__ u16 Ts[4][64][40];    // cos_hi, cos_lo, sin_hi, sin_lo  [m][j]
  __shared__ u16 Vs[2][128][40];   // v_hi, v_lo                      [i][j]
  int zz = blockIdx.z;
  int srcs = (zz >= P) ? 1 : 0;
  int ks = zz - srcs * P;
  int b = blockIdx.y;
  int m0 = blockIdx.x << 6;
  const u16* vhp = srcs ? shp : dhp;
  const u16* vlp = srcs ? slp : dlp;
  float2* __restrict__ dst = (srcs ? Sp : Dp) + (size_t)ks * ((size_t)BB * CKD * l);
  int kstart = ks * chunk;
  int kcnt = n - kstart; if (kcnt > chunk) kcnt = chunk; if (kcnt < 0) kcnt = 0;
  int kmax = kstart + kcnt;
  int t = threadIdx.x, ln = t & 63, w = t >> 6;
  int wm = (w >> 1) << 5, wi = (w & 1) << 6;
  f32x4 accr[2][4], acci[2][4];
  #pragma unroll
  for (int a = 0; a < 2; a++)
    #pragma unroll
    for (int d = 0; d < 4; d++) {
      accr[a][d] = (f32x4){0.f,0.f,0.f,0.f};
      acci[a][d] = (f32x4){0.f,0.f,0.f,0.f};
    }
  const u16* tp0 = tch; const u16* tp1 = tcl; const u16* tp2 = tsh; const u16* tp3 = tsl;

  for (int js = 0; js < kcnt; js += 32) {
    #pragma unroll
    for (int it = 0; it < 4; it++) {     // stage T: 4 planes x 64 rows x 4 chunks
      int idx = t + (it << 8);
      int p = idx >> 8, r = (idx >> 2) & 63, jc = idx & 3;
      int jg = kstart + js + (jc << 3);
      ushort8 v = {0,0,0,0,0,0,0,0};
      int mrow = m0 + r;
      if (mrow < l && jg < kmax) {
        const u16* sp = (p == 0 ? tp0 : p == 1 ? tp1 : p == 2 ? tp2 : tp3)
                        + (size_t)mrow * n + jg;
        if (jg + 8 <= kmax) v = *(const ushort8*)sp;
        else { for (int e = 0; e < 8; e++) if (jg + e < kmax) v[e] = sp[e]; }
      }
      *(ushort8*)&Ts[p][r][jc << 3] = v;
    }
    #pragma unroll
    for (int it = 0; it < 4; it++) {     // stage V: 2 planes x 128 rows x 4 chunks
      int idx = t + (it << 8);
      int p = idx >> 9, r = (idx >> 2) & 127, jc = idx & 3;
      int jg = kstart + js + (jc << 3);
      ushort8 v = {0,0,0,0,0,0,0,0};
      if (jg < kmax) {
        const u16* bp = (p ? vlp : vhp) + ((size_t)b * CKD + r) * n + jg;
        if (jg + 8 <= kmax) v = *(const ushort8*)bp;
        else { for (int e = 0; e < 8; e++) if (jg + e < kmax) v[e] = bp[e]; }
      }
      *(ushort8*)&Vs[p][r][jc << 3] = v;
    }
    __syncthreads();
    int ac = (ln >> 4) << 3;
    #pragma unroll
    for (int fm = 0; fm < 2; fm++) {
      int ar = wm + (fm << 4) + (ln & 15);
      bf16x8 ach = *(const bf16x8*)&Ts[0][ar][ac];
      bf16x8 acl = *(const bf16x8*)&Ts[1][ar][ac];
      bf16x8 ash = *(const bf16x8*)&Ts[2][ar][ac];
      bf16x8 asl = *(const bf16x8*)&Ts[3][ar][ac];
      #pragma unroll
      for (int fi = 0; fi < 4; fi++) {
        int br = wi + (fi << 4) + (ln & 15);
        bf16x8 bh = *(const bf16x8*)&Vs[0][br][ac];
        bf16x8 bl = *(const bf16x8*)&Vs[1][br][ac];
        accr[fm][fi] = __builtin_amdgcn_mfma_f32_16x16x32_bf16(ach, bh, accr[fm][fi], 0, 0, 0);
        accr[fm][fi] = __builtin_amdgcn_mfma_f32_16x16x32_bf16(ach, bl, accr[fm][fi], 0, 0, 0);
        accr[fm][fi] = __builtin_amdgcn_mfma_f32_16x16x32_bf16(acl, bh, accr[fm][fi], 0, 0, 0);
        acci[fm][fi] = __builtin_amdgcn_mfma_f32_16x16x32_bf16(ash, bh, acci[fm][fi], 0, 0, 0);
        acci[fm][fi] = __builtin_amdgcn_mfma_f32_16x16x32_bf16(ash, bl, acci[fm][fi], 0, 0, 0);
        acci[fm][fi] = __builtin_amdgcn_mfma_f32_16x16x32_bf16(asl, bh, acci[fm][fi], 0, 0, 0);
      }
    }
    __syncthreads();
  }
  #pragma unroll
  for (int fm = 0; fm < 2; fm++)
    #pragma unroll
    for (int fi = 0; fi < 4; fi++) {
      int i = wi + (fi << 4) + (ln & 15);
      int mb = m0 + wm + (fm << 4) + ((ln >> 4) << 2);
      #pragma unroll
      for (int rg = 0; rg < 4; rg++) {
        int m = mb + rg;
        if (m < l)
          dst[((size_t)b * l + m) * CKD + i] = make_float2(accr[fm][fi][rg], -acci[fm][fi][rg]);
      }
    }
}

// sum P partial spectra (scratch) into compact Dall/Sall slots
__global__ void reduce_k(float4* __restrict__ dD, float4* __restrict__ dS,
                         const float4* __restrict__ pD, const float4* __restrict__ pS,
                         int cnt4, int P) {
  int idx = blockIdx.x * blockDim.x + threadIdx.x;
  if (idx >= 2 * cnt4) return;
  const float4* src = (idx < cnt4) ? pD : pS;
  float4* dst = (idx < cnt4) ? dD : dS;
  int e = (idx < cnt4) ? idx : idx - cnt4;
  float4 a = src[e];
  for (int p = 1; p < P; p++) {
    float4 v = src[(size_t)p * cnt4 + e];
    a.x += v.x; a.y += v.y; a.z += v.z; a.w += v.w;
  }
  dst[e] = a;
}

// weight transpose+convert: W[i][o][m] fp32 -> 6 bf16-hi planes [m][i][o]
// plane order: 0=Ar 1=Ai 2=Br 3=Bi 4=Cr 5=Ci, stride PSW
__global__ void wtr_k(const float* __restrict__ Ar, const float* __restrict__ Ai,
                      const float* __restrict__ Br, const float* __restrict__ Bi,
                      const float* __restrict__ Cr, const float* __restrict__ Ci,
                      u16* __restrict__ Wp) {
  __shared__ float2 Ts[32][130];
  int i = blockIdx.x;
  int o0 = blockIdx.y << 5;
  int z = blockIdx.z;
  const float* Wr = (z == 0) ? Ar : ((z == 1) ? Br : Cr);
  const float* Wi = (z == 0) ? Ai : ((z == 1) ? Bi : Ci);
  int tid = threadIdx.x;
  {
    int o = tid >> 3, m0 = (tid & 7) << 4;
    const float* rp = Wr + ((size_t)i * CKD + o0 + o) * AL + m0;
    const float* ip = Wi + ((size_t)i * CKD + o0 + o) * AL + m0;
    #pragma unroll
    for (int r = 0; r < 4; r++) {
      float4 vr = *(const float4*)(rp + r * 4);
      float4 vi = *(const float4*)(ip + r * 4);
      Ts[o][m0 + r*4 + 0] = make_float2(vr.x, vi.x);
      Ts[o][m0 + r*4 + 1] = make_float2(vr.y, vi.y);
      Ts[o][m0 + r*4 + 2] = make_float2(vr.z, vi.z);
      Ts[o][m0 + r*4 + 3] = make_float2(vr.w, vi.w);
    }
  }
  __syncthreads();
  {
    int m = tid >> 1, oh = (tid & 1) << 4;
    u16* pr = Wp + (size_t)(2 * z) * PSW + ((size_t)m * CKD + i) * CKD + o0 + oh;
    u16* pi = pr + PSW;
    ushort8 a0, a1, b0, b1;
    #pragma unroll
    for (int r = 0; r < 8; r++) {
      float2 e0 = Ts[oh + r][m];
      float2 e1 = Ts[oh + 8 + r][m];
      a0[r] = f2bh(e0.x); b0[r] = f2bh(e0.y);
      a1[r] = f2bh(e1.x); b1[r] = f2bh(e1.y);
    }
    *(ushort8*)pr = a0;       *(ushort8*)(pr + 8) = a1;
    *(ushort8*)pi = b0;       *(ushort8*)(pi + 8) = b1;
  }
}

// batched per-(lev,m) complex GEMM; bf16 weights; outputs 4 bf16-hi planes [b][m][o]
// plane order: 0=Ur 1=Ui 2=Vr 3=Vi ; plane stride ps
__global__ void __launch_bounds__(256)
mix2_k(const float2* __restrict__ Dall, const float2* __restrict__ Sall,
       const u16* __restrict__ Wp,
       u16* __restrict__ Up4, long long ps, MixTab2 mt) {
  __shared__ __align__(16) float2 Dl[CKD][BB];
  __shared__ __align__(16) float2 Sl[CKD][BB];
  int bx = blockIdx.x;
  int lev = 0;
  #pragma unroll
  for (int q = 1; q < NLEV; q++) lev = (bx >= mt.mcum[q]) ? q : lev;
  int m = bx - mt.mcum[lev];
  int l = mt.l[lev];
  const float2* __restrict__ D = Dall + mt.off[lev];
  const float2* __restrict__ S = Sall + mt.off[lev];
  u16* __restrict__ Ub = Up4 + mt.off[lev];
  int tid = threadIdx.x;
  int o = tid & (CKD - 1), bh = tid >> 7;
  {
    int bq = tid & 15, i0 = (tid >> 4) << 3;
    const float2* Db = D + ((size_t)bq * l + m) * CKD + i0;
    const float2* Sb = S + ((size_t)bq * l + m) * CKD + i0;
    #pragma unroll
    for (int r = 0; r < 8; r++) {
      Dl[i0 + r][bq] = Db[r];
      Sl[i0 + r][bq] = Sb[r];
    }
  }
  __syncthreads();
  float ur[8], ui[8], vr[8], vi[8];
  #pragma unroll
  for (int r = 0; r < 8; r++) { ur[r] = 0.f; ui[r] = 0.f; vr[r] = 0.f; vi[r] = 0.f; }
  const u16* wp0 = Wp + (size_t)m * CKD * CKD + o;
  #pragma unroll 4
  for (int i = 0; i < CKD; i++) {
    size_t wb = (size_t)i * CKD;
    float a_r = bh2f(wp0[wb]);
    float a_i = bh2f(wp0[PSW + wb]);
    float b_r = bh2f(wp0[2 * PSW + wb]);
    float b_i = bh2f(wp0[3 * PSW + wb]);
    float c_r = bh2f(wp0[4 * PSW + wb]);
    float c_i = bh2f(wp0[5 * PSW + wb]);
    float2 dv[8], sv[8];
    #pragma unroll
    for (int r = 0; r < 4; r++) {
      *(float4*)&dv[r*2] = *(const float4*)&Dl[i][(bh << 3) + r*2];
      *(float4*)&sv[r*2] = *(const float4*)&Sl[i][(bh << 3) + r*2];
    }
    #pragma unroll
    for (int r = 0; r < 8; r++) {
      float2 d = dv[r], s = sv[r];
      ur[r] = fmaf(d.x, a_r, ur[r]);  ur[r] = fmaf(-d.y, a_i, ur[r]);
      ur[r] = fmaf(s.x, b_r, ur[r]);  ur[r] = fmaf(-s.y, b_i, ur[r]);
      ui[r] = fmaf(d.x, a_i, ui[r]);  ui[r] = fmaf(d.y, a_r, ui[r]);
      ui[r] = fmaf(s.x, b_i, ui[r]);  ui[r] = fmaf(s.y, b_r, ui[r]);
      vr[r] = fmaf(d.x, c_r, vr[r]);  vr[r] = fmaf(-d.y, c_i, vr[r]);
      vi[r] = fmaf(d.x, c_i, vi[r]);  vi[r] = fmaf(d.y, c_r, vi[r]);
    }
  }
  #pragma unroll
  for (int r = 0; r < 8; r++) {
    int bq = (bh << 3) + r;
    size_t ob = ((size_t)bq * l + m) * CKD + o;
    Ub[ob] = f2bh(ur[r]);
    Ub[(size_t)ps + ob] = f2bh(ui[r]);
    Ub[2 * (size_t)ps + ob] = f2bh(vr[r]);
    Ub[3 * (size_t)ps + ob] = f2bh(vi[r]);
  }
}

// transpose G planes [b][m][o] -> [b][o][m]; grid (NLEV*BB, 4 planes)
__global__ void gt_k(const u16* __restrict__ in, u16* __restrict__ outp,
                     long long ps, MixTab2 mt) {
  __shared__ u16 T[128][136];
  int bx = blockIdx.x;
  int lev = bx >> 4, b = bx & 15;
  int p = blockIdx.y;
  int l = mt.l[lev];
  const u16* ip = in + (size_t)p * ps + mt.off[lev];
  u16* op = outp + (size_t)p * ps + mt.off[lev];
  int tid = threadIdx.x;
  int o8 = (tid & 15) << 3;
  for (int mm = tid >> 4; mm < l; mm += 16) {
    ushort8 v = *(const ushort8*)(ip + ((size_t)b * l + mm) * CKD + o8);
    #pragma unroll
    for (int e = 0; e < 8; e++) T[o8 + e][mm] = v[e];
  }
  __syncthreads();
  bool fast = ((l & 7) == 0);
  int m8 = (tid & 15) << 3;
  for (int o = tid >> 4; o < CKD; o += 16) {
    if (m8 < l) {
      u16* dst = op + ((size_t)b * CKD + o) * l + m8;
      if (fast && m8 + 8 <= l) {
        ushort8 v;
        #pragma unroll
        for (int e = 0; e < 8; e++) v[e] = T[o][m8 + e];
        *(ushort8*)dst = v;
      } else {
        for (int e = 0; m8 + e < l; e++) dst[e] = T[o][m8 + e];
      }
    }
  }
}

// ---- MFMA inverse DFT v3 (bf16-hi only, LDS-staged, single phase per m-chunk) ----
// y[b,j,o] = (2*sum_m(Gr*cos + Gi*(-sin)) - G0.re - nyq*(-1)^j*Gl.re)/n
// block 256 = 4 waves; tile 64j x 128o; wave = 32j x 64o; K = m chunks of 32.
// Stages {cos-hi, (-sin)-hi} A planes + {Gr-hi, Gi-hi} B planes per chunk; 2 MFMA/frag.
// grid: x = ceil(n/64), y = b, z = {U->ud, V->us}; G group = 2 planes at stride ps
__global__ void __launch_bounds__(256)
inv_mfma_k(const u16* __restrict__ GU, const u16* __restrict__ GV, long long ps,
           const u16* __restrict__ tch, const u16* __restrict__ tsh,  // sin pre-negated
           float* __restrict__ ud, float* __restrict__ us,
           int n, int l, int nyq) {
  __shared__ u16 Ts[2][64][40];    // A: cos-hi, (-sin)-hi  [j][m]
  __shared__ u16 Gs[2][128][40];   // B: Gr-hi, Gi-hi       [o][m]
  int z = blockIdx.z;
  const u16* __restrict__ G = z ? GV : GU;
  float* __restrict__ out = z ? us : ud;
  int b = blockIdx.y;
  int j0 = blockIdx.x << 6;
  int t = threadIdx.x, ln = t & 63, w = t >> 6;
  int wj = (w >> 1) << 5;
  int wo = (w & 1) << 6;
  int lr = ln & 15, kq = ln >> 4;
  f32x4 acc[2][4];
  #pragma unroll
  for (int a = 0; a < 2; a++)
    #pragma unroll
    for (int d = 0; d < 4; d++) acc[a][d] = (f32x4){0.f,0.f,0.f,0.f};
  int nch = (l + 31) >> 5;
  for (int mc = 0; mc < nch; mc++) {
    int ms = mc << 5;
    #pragma unroll
    for (int it = 0; it < 2; it++) {   // stage A: 2 planes x 64 rows x 4 chunks
      int idx = t + (it << 8);
      int p = idx >> 8, r = (idx >> 2) & 63, jc = idx & 3;
      int jg = j0 + r;
      int mg = ms + (jc << 3);
      ushort8 v = {0,0,0,0,0,0,0,0};
      if (jg < n && mg < l) {
        const u16* sp = (p ? tsh : tch) + (size_t)jg * l + mg;
        if (mg + 8 <= l) v = *(const ushort8*)sp;
        else { for (int e = 0; e < 8; e++) if (mg + e < l) v[e] = sp[e]; }
      }
      *(ushort8*)&Ts[p][r][jc << 3] = v;
    }
    #pragma unroll
    for (int it = 0; it < 4; it++) {   // stage B: 2 planes x 128 rows x 4 chunks
      int idx = t + (it << 8);
      int p = idx >> 9, r = (idx >> 2) & 127, jc = idx & 3;
      int mg = ms + (jc << 3);
      ushort8 v = {0,0,0,0,0,0,0,0};
      if (mg < l) {
        const u16* bp = (p ? G + (size_t)ps : G) + ((size_t)b * CKD + r) * l + mg;
        if (mg + 8 <= l) v = *(const ushort8*)bp;
        else { for (int e = 0; e < 8; e++) if (mg + e < l) v[e] = bp[e]; }
      }
      *(ushort8*)&Gs[p][r][jc << 3] = v;
    }
    __syncthreads();
    int ac = kq << 3;
    #pragma unroll
    for (int fm = 0; fm < 2; fm++) {
      int ar = wj + (fm << 4) + lr;
      bf16x8 ch = *(const bf16x8*)&Ts[0][ar][ac];
      bf16x8 sh_ = *(const bf16x8*)&Ts[1][ar][ac];
      #pragma unroll
      for (int fi = 0; fi < 4; fi++) {
        int br = wo + (fi << 4) + lr;
        bf16x8 gr = *(const bf16x8*)&Gs[0][br][ac];
        bf16x8 gi = *(const bf16x8*)&Gs[1][br][ac];
        acc[fm][fi] = __builtin_amdgcn_mfma_f32_16x16x32_bf16(ch, gr, acc[fm][fi], 0, 0, 0);
        acc[fm][fi] = __builtin_amdgcn_mfma_f32_16x16x32_bf16(sh_, gi, acc[fm][fi], 0, 0, 0);
      }
    }
    __syncthreads();
  }
  float invn = 1.f / (float)n;
  #pragma unroll
  for (int fi = 0; fi < 4; fi++) {
    int o = wo + (fi << 4) + lr;
    size_t gb = ((size_t)b * CKD + o) * l;
    float g0 = bh2f(G[gb]);
    float gn = nyq ? bh2f(G[gb + l - 1]) : 0.f;
    #pragma unroll
    for (int fm = 0; fm < 2; fm++) {
      int jb = j0 + wj + (fm << 4) + (kq << 2);
      #pragma unroll
      for (int rg = 0; rg < 4; rg++) {
        int j = jb + rg;
        if (j < n) {
          float sgn = (j & 1) ? -1.f : 1.f;
          out[((size_t)b * n + j) * CKD + o] = (2.f * acc[fm][fi][rg] - g0 - sgn * gn) * invn;
        }
      }
    }
  }
}

// coarsest map: y = x @ T0_w^T + T0_b
__global__ void t0_k(const float* __restrict__ xin, const float* __restrict__ w,
                     const float* __restrict__ bv, float* __restrict__ xout) {
  int idx = blockIdx.x * blockDim.x + threadIdx.x;
  if (idx >= BB * CC * KK) return;
  int k = idx & 3;
  int bc = idx >> 2;
  float a = bv[k];
  #pragma unroll
  for (int kp = 0; kp < 4; kp++) a = fmaf(xin[bc*4 + kp], w[k*4 + kp], a);
  xout[idx] = a;
}

__global__ void recon_k(const float* __restrict__ xin, const float* __restrict__ usl,
                        const float* __restrict__ udl,
                        const float* __restrict__ rce, const float* __restrict__ rco,
                        float* __restrict__ xout, int nh) {
  int idx = blockIdx.x * blockDim.x + threadIdx.x;
  if (idx >= BB * nh * CC) return;
  int c = idx & (CC - 1);
  int t = idx / CC;
  int j = t % nh;
  int b = t / nh;
  size_t ib = (((size_t)b * nh + j) * CC + c) * KK;
  float4 xv = *(const float4*)(xin + ib);
  float4 uv = *(const float4*)(usl + ib);
  float4 dv = *(const float4*)(udl + ib);
  float xx[8] = {xv.x+uv.x, xv.y+uv.y, xv.z+uv.z, xv.w+uv.w, dv.x, dv.y, dv.z, dv.w};
  float ev[4] = {0.f,0.f,0.f,0.f}, ov[4] = {0.f,0.f,0.f,0.f};
  #pragma unroll
  for (int p = 0; p < 8; p++) {
    float v = xx[p];
    #pragma unroll
    for (int k = 0; k < 4; k++) {
      ev[k] = fmaf(v, rce[p*4+k], ev[k]);
      ov[k] = fmaf(v, rco[p*4+k], ov[k]);
    }
  }
  size_t ob = (((size_t)b * (2*nh) + 2*j) * CC + c) * KK;
  *(float4*)(xout + ob) = make_float4(ev[0], ev[1], ev[2], ev[3]);
  *(float4*)(xout + ob + CC*KK) = make_float4(ov[0], ov[1], ov[2], ov[3]);
}

extern "C" void kernel_launch(void* const* d_in, const int* in_sizes, int n_in,
                              void* d_out, int out_size, void* d_ws, size_t ws_size,
                              hipStream_t stream) {
  const float* x   = (const float*)d_in[0];
  const float* wAr = (const float*)d_in[1];
  const float* wAi = (const float*)d_in[2];
  const float* wBr = (const float*)d_in[3];
  const float* wBi = (const float*)d_in[4];
  const float* wCr = (const float*)d_in[5];
  const float* wCi = (const float*)d_in[6];
  const float *ecs, *ecd, *rce, *rco, *t0w, *t0b;
  if (in_sizes[7] == 16) {
    t0w = (const float*)d_in[7];  t0b = (const float*)d_in[8];
    ecs = (const float*)d_in[9];  ecd = (const float*)d_in[10];
    rce = (const float*)d_in[11]; rco = (const float*)d_in[12];
  } else {
    ecs = (const float*)d_in[7];  ecd = (const float*)d_in[8];
    rce = (const float*)d_in[9];  rco = (const float*)d_in[10];
    t0w = (const float*)d_in[11]; t0b = (const float*)d_in[12];
  }

  int nh[NLEV], lv[NLEV];
  size_t twoff[NLEV], spoff[NLEV];
  size_t tacc = 0, spacc = 0;
  for (int q = 0; q < NLEV; q++) {
    nh[q] = NN >> (q + 1);
    int li = nh[q] / 2 + 1;
    lv[q] = li < AL ? li : AL;
    twoff[q] = tacc; tacc += (size_t)nh[q] * lv[q];
    spoff[q] = spacc; spacc += (size_t)BB * CKD * lv[q];
  }

  float* ws = (float*)d_ws;
  const size_t XS = (size_t)BB * (NN/2) * CKD;     // 8,388,608 floats
  float*  xb0  = ws;                               // XS floats
  float*  xb1  = xb0 + XS;                         // XS/2 floats (recon even-q outputs fit EXACTLY)
  float2* Dall = (float2*)(xb1 + XS / 2);          // spacc float2, fwd spectra [b][m][i]; later Gt4
  float2* Sall = Dall + spacc;
  float2* Uall = Sall + spacc;                     // 4 u16 planes (mix out) / fwd scrD
  float2* Vall = Uall + spacc;
  float*  udT  = (float*)(Vall + spacc);           // XS floats: fwd dh/dl; Wt planes; recon ud
  float*  usT  = udT + XS;                         // XS floats: fwd sh/sl; recon us; t0buf tail
  // inverse twiddle planes [j][m] (sin negated), 4 x tacc u16 (lo planes unused by v3)
  u16* tjch = (u16*)(usT + XS);
  u16* tjcl = tjch + tacc;
  u16* tjsh = tjcl + tacc;
  u16* tjsl = tjsh + tacc;
  // forward twiddle planes [m][j], 4 x tacc u16
  u16* twCh = tjsl + tacc;
  u16* twCl = twCh + tacc;
  u16* twSh = twCl + tacc;
  u16* twSl = twSh + tacc;
  // bf16 source planes: [b][CKD][n], level-0 sized
  u16* dhp = (u16*)udT;
  u16* dlp = dhp + (size_t)BB * CKD * (NN/2);
  u16* shp = (u16*)usT;
  u16* slp = shp + (size_t)BB * CKD * (NN/2);
  float2* scrD = Uall;                             // fwd K-split D partials
  u16* WtP = (u16*)udT;                            // 6 bf16 weight planes (mix time), 25.2 MB
  u16* Up4 = (u16*)Uall;                           // mix output: 4 planes [b][m][o]
  u16* Gt4 = (u16*)Dall;                           // transposed G: 4 planes [b][o][m] — survives to q=0
  float* t0buf = usT + XS - 4096;                  // 2048 floats; dead tail of usT

  LevTab lt;
  for (int q = 0; q < NLEV; q++) { lt.off[q] = (int)twoff[q]; lt.n[q] = nh[q]; lt.l[q] = lv[q]; }
  lt.total = (int)tacc;
  twiddle_fill_k<<<dim3((unsigned)((tacc + 255) / 256)), 256, 0, stream>>>(
      tjch, tjcl, tjsh, tjsl, twCh, twCl, twSh, twSl, lt);

  // ---------- decompose(+transpose/convert) + MFMA forward DFT ----------
  const float* cur = x;
  float* nxt = xb0;
  for (int q = 0; q < NLEV; q++) {
    int n2 = nh[q], l = lv[q];
    decomp_t_k<<<dim3((n2 + 63) / 64, BB), 256, 0, stream>>>(cur, nxt, dhp, dlp, shp, slp,
                                                             ecs, ecd, n2);
    int P = (n2 >= 512) ? 8 : ((n2 >= 64) ? n2 / 64 : 1);
    int chunk = ((n2 + P - 1) / P + 31) & ~31;
    int mtiles = (l + 63) / 64;
    float* curbuf = (q == 0) ? xb1 : ((q & 1) ? xb0 : xb1);
    float2* Dp = (P > 1) ? scrD : (Dall + spoff[q]);
    float2* Sp = (P > 1) ? (float2*)curbuf : (Sall + spoff[q]);
    fwd_mfma_k<<<dim3(mtiles, BB, 2 * P), 256, 0, stream>>>(
        dhp, dlp, shp, slp,
        twCh + twoff[q], twCl + twoff[q], twSh + twoff[q], twSl + twoff[q],
        Dp, Sp, n2, l, P, chunk);
    if (P > 1) {
      int cnt4 = (BB * CKD * l) / 2;
      reduce_k<<<dim3((2 * cnt4 + 255) / 256), 256, 0, stream>>>(
          (float4*)(Dall + spoff[q]), (float4*)(Sall + spoff[q]),
          (const float4*)scrD, (const float4*)Sp, cnt4, P);
    }
    cur = nxt;
    nxt = (nxt == xb0) ? xb1 : xb0;
  }

  // ---------- transpose+convert weights into 6 bf16 planes [m][i][o] ----------
  wtr_k<<<dim3(CKD, 4, 3), 256, 0, stream>>>(wAr, wAi, wBr, wBi, wCr, wCi, WtP);

  // ---------- batched per-(lev,m) complex GEMM mode-mix ----------
  MixTab2 mt;
  int mc = 0;
  for (int q = 0; q < NLEV; q++) {
    mt.off[q] = (long long)spoff[q];
    mt.l[q] = lv[q];
    mt.mcum[q] = mc;
    mc += lv[q];
  }
  mix2_k<<<dim3((unsigned)mc), 256, 0, stream>>>(Dall, Sall, WtP,
                                                 Up4, (long long)spacc, mt);

  // ---------- transpose G planes [b][m][o] -> [b][o][m] (Dall/Sall dead post-mix) ----------
  gt_k<<<dim3(NLEV * BB, 4), 256, 0, stream>>>(Up4, Gt4, (long long)spacc, mt);

  // ---------- coarsest linear map (to usT-tail scratch; xb0/xb1 reserved for recon) ----------
  t0_k<<<dim3((BB * CC * KK + 255) / 256), 256, 0, stream>>>(cur, t0w, t0b, t0buf);

  // ---------- reconstruct (MFMA inverse DFT per level) ----------
  const float* rcur = t0buf;
  for (int q = NLEV - 1; q >= 0; q--) {
    int n2 = nh[q], l = lv[q];
    int nyq = (((n2 & 1) == 0) && (l == n2 / 2 + 1)) ? 1 : 0;
    inv_mfma_k<<<dim3((n2 + 63) / 64, BB, 2), 256, 0, stream>>>(
        Gt4 + spoff[q], Gt4 + 2 * spacc + spoff[q], (long long)spacc,
        tjch + twoff[q], tjsh + twoff[q],
        udT, usT, n2, l, nyq);
    float* outp = (q == 0) ? (float*)d_out : ((q & 1) ? xb0 : xb1);
    int tot = BB * n2 * CC;
    recon_k<<<dim3((tot + 255) / 256), 256, 0, stream>>>(rcur, usT, udT,
                                                         rce, rco, outp, n2);
    rcur = outp;
  }
}

// Round 10
// 796.448 us; speedup vs baseline: 1.4763x; 1.0864x over previous
//
#include <hip/hip_runtime.h>

#define BB 16
#define CC 32
#define KK 4
#define CKD 128     // C*K
#define NN 8192
#define NLEV 13
#define AL 128      // ALPHA (weight mode-axis storage stride)
#define PSW ((size_t)CKD * CKD * AL)   // weight plane stride (u16 elems)

typedef unsigned short u16;
typedef __attribute__((ext_vector_type(8))) short bf16x8;
typedef __attribute__((ext_vector_type(8))) unsigned short ushort8;
typedef __attribute__((ext_vector_type(4))) float f32x4;

struct LevTab { int off[NLEV]; int n[NLEV]; int l[NLEV]; int total; };
struct MixTab2 { long long off[NLEV]; int l[NLEV]; int mcum[NLEV]; };

__device__ __forceinline__ u16 f2bh(float x) {
  union { float f; unsigned u; } v; v.f = x;
  unsigned r = (v.u + 0x7fffu + ((v.u >> 16) & 1u)) >> 16;
  return (u16)r;
}
__device__ __forceinline__ float bh2f(u16 h) {
  union { unsigned u; float f; } v; v.u = ((unsigned)h) << 16; return v.f;
}

// inverse A planes [j][m] (sin NEGATED, hi/lo) + forward planes [m][j]
__global__ void twiddle_fill_k(u16* __restrict__ tjch, u16* __restrict__ tjcl,
                               u16* __restrict__ tjsh, u16* __restrict__ tjsl,
                               u16* __restrict__ tch, u16* __restrict__ tcl,
                               u16* __restrict__ tsh, u16* __restrict__ tsl, LevTab t) {
  int idx = blockIdx.x * blockDim.x + threadIdx.x;
  if (idx >= t.total) return;
  int lev = 0;
  for (int q = 1; q < NLEV; q++) lev = (idx >= t.off[q]) ? q : lev;
  int r = idx - t.off[lev];
  int n = t.n[lev], l = t.l[lev];
  int j = r / l, m = r - j * l;
  long long pp = ((long long)j * (long long)m) % n;
  float ang = (float)((double)pp * (6.283185307179586476925286766559 / (double)n));
  float s, c;
  sincosf(ang, &s, &c);
  size_t oj = (size_t)idx;
  u16 h = f2bh(c); tjch[oj] = h; tjcl[oj] = f2bh(c - bh2f(h));
  float ns = -s;
  h = f2bh(ns); tjsh[oj] = h; tjsl[oj] = f2bh(ns - bh2f(h));
  size_t om = (size_t)t.off[lev] + (size_t)m * n + j;
  h = f2bh(c); tch[om] = h; tcl[om] = f2bh(c - bh2f(h));
  h = f2bh(s); tsh[om] = h; tsl[om] = f2bh(s - bh2f(h));
}

// fused decompose + transpose/convert:
// x:(B,2nh,CKD) fp32 -> s:(B,nh,CKD) fp32 (next level input)
//                    -> dh/dl/sh/sl: (B,CKD,nh) bf16 split planes (MFMA operands)
__global__ void decomp_t_k(const float* __restrict__ xin, float* __restrict__ sout,
                           u16* __restrict__ dh, u16* __restrict__ dl,
                           u16* __restrict__ sh, u16* __restrict__ sl,
                           const float* __restrict__ ecs, const float* __restrict__ ecd,
                           int nh) {
  int b = blockIdx.y;
  int j0 = blockIdx.x << 6;
  int t = threadIdx.x;
  int c = t & 31, j8 = t >> 5;
  int jbase = j0 + (j8 << 3);
  float s8[4][8], d8[4][8];
  #pragma unroll
  for (int jj = 0; jj < 8; jj++) {
    int j = jbase + jj;
    float sv[4] = {0.f,0.f,0.f,0.f}, dv[4] = {0.f,0.f,0.f,0.f};
    if (j < nh) {
      size_t ib = (((size_t)b * 2 * nh + 2 * j) * CC + c) * KK;
      float4 xe = *(const float4*)(xin + ib);
      float4 xo = *(const float4*)(xin + ib + CC * KK);
      float xa[8] = {xe.x, xe.y, xe.z, xe.w, xo.x, xo.y, xo.z, xo.w};
      #pragma unroll
      for (int p = 0; p < 8; p++) {
        float v = xa[p];
        #pragma unroll
        for (int k = 0; k < 4; k++) {
          sv[k] = fmaf(v, ecs[p*4+k], sv[k]);
          dv[k] = fmaf(v, ecd[p*4+k], dv[k]);
        }
      }
      size_t ob = (((size_t)b * nh + j) * CC + c) * KK;
      *(float4*)(sout + ob) = make_float4(sv[0], sv[1], sv[2], sv[3]);
    }
    #pragma unroll
    for (int k = 0; k < 4; k++) { s8[k][jj] = sv[k]; d8[k][jj] = dv[k]; }
  }
  if (jbase < nh) {
    bool full = (jbase + 8 <= nh);
    #pragma unroll
    for (int k = 0; k < 4; k++) {
      int i = (c << 2) + k;
      size_t rb = ((size_t)b * CKD + i) * nh + jbase;
      ushort8 vh, vl, wh, wl;
      #pragma unroll
      for (int jj = 0; jj < 8; jj++) {
        float dvv = d8[k][jj];
        u16 h = f2bh(dvv); vh[jj] = h; vl[jj] = f2bh(dvv - bh2f(h));
        float svv = s8[k][jj];
        h = f2bh(svv); wh[jj] = h; wl[jj] = f2bh(svv - bh2f(h));
      }
      if (full) {
        *(ushort8*)(dh + rb) = vh; *(ushort8*)(dl + rb) = vl;
        *(ushort8*)(sh + rb) = wh; *(ushort8*)(sl + rb) = wl;
      } else {
        int lim = nh - jbase;
        for (int jj = 0; jj < lim; jj++) {
          dh[rb+jj] = vh[jj]; dl[rb+jj] = vl[jj];
          sh[rb+jj] = wh[jj]; sl[rb+jj] = wl[jj];
        }
      }
    }
  }
}

// ---- MFMA forward DFT (split-bf16, 3 mfma per product) ----
__global__ void __launch_bounds__(256)
fwd_mfma_k(const u16* __restrict__ dhp, const u16* __restrict__ dlp,
           const u16* __restrict__ shp, const u16* __restrict__ slp,
           const u16* __restrict__ tch, const u16* __restrict__ tcl,
           const u16* __restrict__ tsh, const u16* __restrict__ tsl,
           float2* __restrict__ Dp, float2* __restrict__ Sp,
           int n, int l, int P, int chunk) {
  __shared__ u16 Ts[4][64][40];    // cos_hi, cos_lo, sin_hi, sin_lo  [m][j]
  __shared__ u16 Vs[2][128][40];   // v_hi, v_lo                      [i][j]
  int zz = blockIdx.z;
  int srcs = (zz >= P) ? 1 : 0;
  int ks = zz - srcs * P;
  int b = blockIdx.y;
  int m0 = blockIdx.x << 6;
  const u16* vhp = srcs ? shp : dhp;
  const u16* vlp = srcs ? slp : dlp;
  float2* __restrict__ dst = (srcs ? Sp : Dp) + (size_t)ks * ((size_t)BB * CKD * l);
  int kstart = ks * chunk;
  int kcnt = n - kstart; if (kcnt > chunk) kcnt = chunk; if (kcnt < 0) kcnt = 0;
  int kmax = kstart + kcnt;
  int t = threadIdx.x, ln = t & 63, w = t >> 6;
  int wm = (w >> 1) << 5, wi = (w & 1) << 6;
  f32x4 accr[2][4], acci[2][4];
  #pragma unroll
  for (int a = 0; a < 2; a++)
    #pragma unroll
    for (int d = 0; d < 4; d++) {
      accr[a][d] = (f32x4){0.f,0.f,0.f,0.f};
      acci[a][d] = (f32x4){0.f,0.f,0.f,0.f};
    }
  const u16* tp0 = tch; const u16* tp1 = tcl; const u16* tp2 = tsh; const u16* tp3 = tsl;

  for (int js = 0; js < kcnt; js += 32) {
    #pragma unroll
    for (int it = 0; it < 4; it++) {     // stage T: 4 planes x 64 rows x 4 chunks
      int idx = t + (it << 8);
      int p = idx >> 8, r = (idx >> 2) & 63, jc = idx & 3;
      int jg = kstart + js + (jc << 3);
      ushort8 v = {0,0,0,0,0,0,0,0};
      int mrow = m0 + r;
      if (mrow < l && jg < kmax) {
        const u16* sp = (p == 0 ? tp0 : p == 1 ? tp1 : p == 2 ? tp2 : tp3)
                        + (size_t)mrow * n + jg;
        if (jg + 8 <= kmax) v = *(const ushort8*)sp;
        else { for (int e = 0; e < 8; e++) if (jg + e < kmax) v[e] = sp[e]; }
      }
      *(ushort8*)&Ts[p][r][jc << 3] = v;
    }
    #pragma unroll
    for (int it = 0; it < 4; it++) {     // stage V: 2 planes x 128 rows x 4 chunks
      int idx = t + (it << 8);
      int p = idx >> 9, r = (idx >> 2) & 127, jc = idx & 3;
      int jg = kstart + js + (jc << 3);
      ushort8 v = {0,0,0,0,0,0,0,0};
      if (jg < kmax) {
        const u16* bp = (p ? vlp : vhp) + ((size_t)b * CKD + r) * n + jg;
        if (jg + 8 <= kmax) v = *(const ushort8*)bp;
        else { for (int e = 0; e < 8; e++) if (jg + e < kmax) v[e] = bp[e]; }
      }
      *(ushort8*)&Vs[p][r][jc << 3] = v;
    }
    __syncthreads();
    int ac = (ln >> 4) << 3;
    #pragma unroll
    for (int fm = 0; fm < 2; fm++) {
      int ar = wm + (fm << 4) + (ln & 15);
      bf16x8 ach = *(const bf16x8*)&Ts[0][ar][ac];
      bf16x8 acl = *(const bf16x8*)&Ts[1][ar][ac];
      bf16x8 ash = *(const bf16x8*)&Ts[2][ar][ac];
      bf16x8 asl = *(const bf16x8*)&Ts[3][ar][ac];
      #pragma unroll
      for (int fi = 0; fi < 4; fi++) {
        int br = wi + (fi << 4) + (ln & 15);
        bf16x8 bh = *(const bf16x8*)&Vs[0][br][ac];
        bf16x8 bl = *(const bf16x8*)&Vs[1][br][ac];
        accr[fm][fi] = __builtin_amdgcn_mfma_f32_16x16x32_bf16(ach, bh, accr[fm][fi], 0, 0, 0);
        accr[fm][fi] = __builtin_amdgcn_mfma_f32_16x16x32_bf16(ach, bl, accr[fm][fi], 0, 0, 0);
        accr[fm][fi] = __builtin_amdgcn_mfma_f32_16x16x32_bf16(acl, bh, accr[fm][fi], 0, 0, 0);
        acci[fm][fi] = __builtin_amdgcn_mfma_f32_16x16x32_bf16(ash, bh, acci[fm][fi], 0, 0, 0);
        acci[fm][fi] = __builtin_amdgcn_mfma_f32_16x16x32_bf16(ash, bl, acci[fm][fi], 0, 0, 0);
        acci[fm][fi] = __builtin_amdgcn_mfma_f32_16x16x32_bf16(asl, bh, acci[fm][fi], 0, 0, 0);
      }
    }
    __syncthreads();
  }
  #pragma unroll
  for (int fm = 0; fm < 2; fm++)
    #pragma unroll
    for (int fi = 0; fi < 4; fi++) {
      int i = wi + (fi << 4) + (ln & 15);
      int mb = m0 + wm + (fm << 4) + ((ln >> 4) << 2);
      #pragma unroll
      for (int rg = 0; rg < 4; rg++) {
        int m = mb + rg;
        if (m < l)
          dst[((size_t)b * l + m) * CKD + i] = make_float2(accr[fm][fi][rg], -acci[fm][fi][rg]);
      }
    }
}

// sum P partial spectra (scratch) into compact Dall/Sall slots
__global__ void reduce_k(float4* __restrict__ dD, float4* __restrict__ dS,
                         const float4* __restrict__ pD, const float4* __restrict__ pS,
                         int cnt4, int P) {
  int idx = blockIdx.x * blockDim.x + threadIdx.x;
  if (idx >= 2 * cnt4) return;
  const float4* src = (idx < cnt4) ? pD : pS;
  float4* dst = (idx < cnt4) ? dD : dS;
  int e = (idx < cnt4) ? idx : idx - cnt4;
  float4 a = src[e];
  for (int p = 1; p < P; p++) {
    float4 v = src[(size_t)p * cnt4 + e];
    a.x += v.x; a.y += v.y; a.z += v.z; a.w += v.w;
  }
  dst[e] = a;
}

// weight transpose+convert: W[i][o][m] fp32 -> 6 bf16-hi planes [m][o][i] (i contiguous)
// plane order: 0=Ar 1=Ai 2=Br 3=Bi 4=Cr 5=Ci, stride PSW
// grid (o=CKD, mtile=AL/32, z=3), block 256
__global__ void wtr_k(const float* __restrict__ Ar, const float* __restrict__ Ai,
                      const float* __restrict__ Br, const float* __restrict__ Bi,
                      const float* __restrict__ Cr, const float* __restrict__ Ci,
                      u16* __restrict__ Wp) {
  __shared__ float Tr[128][33];
  __shared__ float Ti[128][33];
  int o = blockIdx.x;
  int m0 = blockIdx.y << 5;
  int z = blockIdx.z;
  const float* Wr = (z == 0) ? Ar : ((z == 1) ? Br : Cr);
  const float* Wi = (z == 0) ? Ai : ((z == 1) ? Bi : Ci);
  int t = threadIdx.x;
  { // load: [128 i][32 m] both planes
    int i = t >> 1, mh = (t & 1) << 4;
    const float* rp = Wr + ((size_t)i * CKD + o) * AL + m0 + mh;
    const float* ip = Wi + ((size_t)i * CKD + o) * AL + m0 + mh;
    #pragma unroll
    for (int q = 0; q < 4; q++) {
      float4 vr = *(const float4*)(rp + q * 4);
      float4 vi = *(const float4*)(ip + q * 4);
      Tr[i][mh + q*4 + 0] = vr.x; Tr[i][mh + q*4 + 1] = vr.y;
      Tr[i][mh + q*4 + 2] = vr.z; Tr[i][mh + q*4 + 3] = vr.w;
      Ti[i][mh + q*4 + 0] = vi.x; Ti[i][mh + q*4 + 1] = vi.y;
      Ti[i][mh + q*4 + 2] = vi.z; Ti[i][mh + q*4 + 3] = vi.w;
    }
  }
  __syncthreads();
  { // store: [32 m][128 i], i contiguous, bf16
    int ml = t >> 3, ic = (t & 7) << 4;
    u16* pr = Wp + (size_t)(2 * z) * PSW + (((size_t)(m0 + ml) * CKD + o) * CKD) + ic;
    u16* pi = pr + PSW;
    ushort8 a0, a1, b0, b1;
    #pragma unroll
    for (int e = 0; e < 8; e++) {
      a0[e] = f2bh(Tr[ic + e][ml]);     b0[e] = f2bh(Ti[ic + e][ml]);
      a1[e] = f2bh(Tr[ic + 8 + e][ml]); b1[e] = f2bh(Ti[ic + 8 + e][ml]);
    }
    *(ushort8*)pr = a0;       *(ushort8*)(pr + 8) = a1;
    *(ushort8*)pi = b0;       *(ushort8*)(pi + 8) = b1;
  }
}

// ---- MFMA mode-mix: per-(lev,m) complex GEMM M=16(b) x N=64(o) x K=128(i) ----
// A (LDS): 6 bf16 planes [b][i]: Dr, Di, -Di, Sr, Si, -Si (stage once, no loop barriers)
// B (global): Wp[p][m][o][i] bf16 fragments, 16B coalesced
// C: Ur,Ui,Vr,Vi -> 4 bf16 planes [b][m][o], stride ps
// grid (sum_l, 2 o-halves), block 256 = 4 waves x one 16-o tile
__global__ void __launch_bounds__(256)
mix3_k(const float2* __restrict__ Dall, const float2* __restrict__ Sall,
       const u16* __restrict__ Wp,
       u16* __restrict__ Up4, long long ps, MixTab2 mt) {
  __shared__ u16 A[6][16][136];
  int bx = blockIdx.x;
  int lev = 0;
  #pragma unroll
  for (int q = 1; q < NLEV; q++) lev = (bx >= mt.mcum[q]) ? q : lev;
  int m = bx - mt.mcum[lev];
  int l = mt.l[lev];
  const float2* __restrict__ D = Dall + mt.off[lev];
  const float2* __restrict__ S = Sall + mt.off[lev];
  u16* __restrict__ Ub = Up4 + mt.off[lev];
  int t = threadIdx.x;
  { // stage D,S [16 b][128 i] -> 6 bf16 planes
    int b = t >> 4, ic = (t & 15) << 3;
    const float2* Dp_ = D + ((size_t)b * l + m) * CKD + ic;
    const float2* Sp_ = S + ((size_t)b * l + m) * CKD + ic;
    ushort8 dr, di, dn, sr, si, sn;
    #pragma unroll
    for (int e = 0; e < 8; e++) {
      float2 d = Dp_[e];
      dr[e] = f2bh(d.x); di[e] = f2bh(d.y); dn[e] = di[e] ^ 0x8000u;
      float2 s = Sp_[e];
      sr[e] = f2bh(s.x); si[e] = f2bh(s.y); sn[e] = si[e] ^ 0x8000u;
    }
    *(ushort8*)&A[0][b][ic] = dr; *(ushort8*)&A[1][b][ic] = di;
    *(ushort8*)&A[2][b][ic] = dn; *(ushort8*)&A[3][b][ic] = sr;
    *(ushort8*)&A[4][b][ic] = si; *(ushort8*)&A[5][b][ic] = sn;
  }
  __syncthreads();
  int ln = t & 63, w = t >> 6;
  int lr = ln & 15, kq = ln >> 4;
  int o0 = (blockIdx.y << 6) + (w << 4);
  f32x4 aUr = (f32x4){0.f,0.f,0.f,0.f}, aUi = aUr, aVr = aUr, aVi = aUr;
  const u16* wb = Wp + (((size_t)m * CKD + o0 + lr) * CKD);
  #pragma unroll 2
  for (int kc = 0; kc < 4; kc++) {
    int i8 = (kc << 5) + (kq << 3);
    bf16x8 Dr = *(const bf16x8*)&A[0][lr][i8];
    bf16x8 Di = *(const bf16x8*)&A[1][lr][i8];
    bf16x8 Dn = *(const bf16x8*)&A[2][lr][i8];
    bf16x8 Sr = *(const bf16x8*)&A[3][lr][i8];
    bf16x8 Si = *(const bf16x8*)&A[4][lr][i8];
    bf16x8 Sn = *(const bf16x8*)&A[5][lr][i8];
    bf16x8 wAr = *(const bf16x8*)(wb + i8);
    bf16x8 wAi = *(const bf16x8*)(wb + PSW + i8);
    bf16x8 wBr = *(const bf16x8*)(wb + 2 * PSW + i8);
    bf16x8 wBi = *(const bf16x8*)(wb + 3 * PSW + i8);
    bf16x8 wCr = *(const bf16x8*)(wb + 4 * PSW + i8);
    bf16x8 wCi = *(const bf16x8*)(wb + 5 * PSW + i8);
    aUr = __builtin_amdgcn_mfma_f32_16x16x32_bf16(Dr, wAr, aUr, 0, 0, 0);
    aUr = __builtin_amdgcn_mfma_f32_16x16x32_bf16(Dn, wAi, aUr, 0, 0, 0);
    aUr = __builtin_amdgcn_mfma_f32_16x16x32_bf16(Sr, wBr, aUr, 0, 0, 0);
    aUr = __builtin_amdgcn_mfma_f32_16x16x32_bf16(Sn, wBi, aUr, 0, 0, 0);
    aUi = __builtin_amdgcn_mfma_f32_16x16x32_bf16(Dr, wAi, aUi, 0, 0, 0);
    aUi = __builtin_amdgcn_mfma_f32_16x16x32_bf16(Di, wAr, aUi, 0, 0, 0);
    aUi = __builtin_amdgcn_mfma_f32_16x16x32_bf16(Sr, wBi, aUi, 0, 0, 0);
    aUi = __builtin_amdgcn_mfma_f32_16x16x32_bf16(Si, wBr, aUi, 0, 0, 0);
    aVr = __builtin_amdgcn_mfma_f32_16x16x32_bf16(Dr, wCr, aVr, 0, 0, 0);
    aVr = __builtin_amdgcn_mfma_f32_16x16x32_bf16(Dn, wCi, aVr, 0, 0, 0);
    aVi = __builtin_amdgcn_mfma_f32_16x16x32_bf16(Dr, wCi, aVi, 0, 0, 0);
    aVi = __builtin_amdgcn_mfma_f32_16x16x32_bf16(Di, wCr, aVi, 0, 0, 0);
  }
  int o = o0 + lr;
  #pragma unroll
  for (int rg = 0; rg < 4; rg++) {
    int b = (kq << 2) + rg;
    size_t ob = ((size_t)b * l + m) * CKD + o;
    Ub[ob] = f2bh(aUr[rg]);
    Ub[(size_t)ps + ob] = f2bh(aUi[rg]);
    Ub[2 * (size_t)ps + ob] = f2bh(aVr[rg]);
    Ub[3 * (size_t)ps + ob] = f2bh(aVi[rg]);
  }
}

// transpose G planes [b][m][o] -> [b][o][m]; grid (NLEV*BB, 4 planes)
__global__ void gt_k(const u16* __restrict__ in, u16* __restrict__ outp,
                     long long ps, MixTab2 mt) {
  __shared__ u16 T[128][136];
  int bx = blockIdx.x;
  int lev = bx >> 4, b = bx & 15;
  int p = blockIdx.y;
  int l = mt.l[lev];
  const u16* ip = in + (size_t)p * ps + mt.off[lev];
  u16* op = outp + (size_t)p * ps + mt.off[lev];
  int tid = threadIdx.x;
  int o8 = (tid & 15) << 3;
  for (int mm = tid >> 4; mm < l; mm += 16) {
    ushort8 v = *(const ushort8*)(ip + ((size_t)b * l + mm) * CKD + o8);
    #pragma unroll
    for (int e = 0; e < 8; e++) T[o8 + e][mm] = v[e];
  }
  __syncthreads();
  bool fast = ((l & 7) == 0);
  int m8 = (tid & 15) << 3;
  for (int o = tid >> 4; o < CKD; o += 16) {
    if (m8 < l) {
      u16* dst = op + ((size_t)b * CKD + o) * l + m8;
      if (fast && m8 + 8 <= l) {
        ushort8 v;
        #pragma unroll
        for (int e = 0; e < 8; e++) v[e] = T[o][m8 + e];
        *(ushort8*)dst = v;
      } else {
        for (int e = 0; m8 + e < l; e++) dst[e] = T[o][m8 + e];
      }
    }
  }
}

// ---- MFMA inverse DFT v3 (bf16-hi only, LDS-staged, single phase per m-chunk) ----
__global__ void __launch_bounds__(256)
inv_mfma_k(const u16* __restrict__ GU, const u16* __restrict__ GV, long long ps,
           const u16* __restrict__ tch, const u16* __restrict__ tsh,  // sin pre-negated
           float* __restrict__ ud, float* __restrict__ us,
           int n, int l, int nyq) {
  __shared__ u16 Ts[2][64][40];    // A: cos-hi, (-sin)-hi  [j][m]
  __shared__ u16 Gs[2][128][40];   // B: Gr-hi, Gi-hi       [o][m]
  int z = blockIdx.z;
  const u16* __restrict__ G = z ? GV : GU;
  float* __restrict__ out = z ? us : ud;
  int b = blockIdx.y;
  int j0 = blockIdx.x << 6;
  int t = threadIdx.x, ln = t & 63, w = t >> 6;
  int wj = (w >> 1) << 5;
  int wo = (w & 1) << 6;
  int lr = ln & 15, kq = ln >> 4;
  f32x4 acc[2][4];
  #pragma unroll
  for (int a = 0; a < 2; a++)
    #pragma unroll
    for (int d = 0; d < 4; d++) acc[a][d] = (f32x4){0.f,0.f,0.f,0.f};
  int nch = (l + 31) >> 5;
  for (int mc = 0; mc < nch; mc++) {
    int ms = mc << 5;
    #pragma unroll
    for (int it = 0; it < 2; it++) {   // stage A: 2 planes x 64 rows x 4 chunks
      int idx = t + (it << 8);
      int p = idx >> 8, r = (idx >> 2) & 63, jc = idx & 3;
      int jg = j0 + r;
      int mg = ms + (jc << 3);
      ushort8 v = {0,0,0,0,0,0,0,0};
      if (jg < n && mg < l) {
        const u16* sp = (p ? tsh : tch) + (size_t)jg * l + mg;
        if (mg + 8 <= l) v = *(const ushort8*)sp;
        else { for (int e = 0; e < 8; e++) if (mg + e < l) v[e] = sp[e]; }
      }
      *(ushort8*)&Ts[p][r][jc << 3] = v;
    }
    #pragma unroll
    for (int it = 0; it < 4; it++) {   // stage B: 2 planes x 128 rows x 4 chunks
      int idx = t + (it << 8);
      int p = idx >> 9, r = (idx >> 2) & 127, jc = idx & 3;
      int mg = ms + (jc << 3);
      ushort8 v = {0,0,0,0,0,0,0,0};
      if (mg < l) {
        const u16* bp = (p ? G + (size_t)ps : G) + ((size_t)b * CKD + r) * l + mg;
        if (mg + 8 <= l) v = *(const ushort8*)bp;
        else { for (int e = 0; e < 8; e++) if (mg + e < l) v[e] = bp[e]; }
      }
      *(ushort8*)&Gs[p][r][jc << 3] = v;
    }
    __syncthreads();
    int ac = kq << 3;
    #pragma unroll
    for (int fm = 0; fm < 2; fm++) {
      int ar = wj + (fm << 4) + lr;
      bf16x8 ch = *(const bf16x8*)&Ts[0][ar][ac];
      bf16x8 sh_ = *(const bf16x8*)&Ts[1][ar][ac];
      #pragma unroll
      for (int fi = 0; fi < 4; fi++) {
        int br = wo + (fi << 4) + lr;
        bf16x8 gr = *(const bf16x8*)&Gs[0][br][ac];
        bf16x8 gi = *(const bf16x8*)&Gs[1][br][ac];
        acc[fm][fi] = __builtin_amdgcn_mfma_f32_16x16x32_bf16(ch, gr, acc[fm][fi], 0, 0, 0);
        acc[fm][fi] = __builtin_amdgcn_mfma_f32_16x16x32_bf16(sh_, gi, acc[fm][fi], 0, 0, 0);
      }
    }
    __syncthreads();
  }
  float invn = 1.f / (float)n;
  #pragma unroll
  for (int fi = 0; fi < 4; fi++) {
    int o = wo + (fi << 4) + lr;
    size_t gb = ((size_t)b * CKD + o) * l;
    float g0 = bh2f(G[gb]);
    float gn = nyq ? bh2f(G[gb + l - 1]) : 0.f;
    #pragma unroll
    for (int fm = 0; fm < 2; fm++) {
      int jb = j0 + wj + (fm << 4) + (kq << 2);
      #pragma unroll
      for (int rg = 0; rg < 4; rg++) {
        int j = jb + rg;
        if (j < n) {
          float sgn = (j & 1) ? -1.f : 1.f;
          out[((size_t)b * n + j) * CKD + o] = (2.f * acc[fm][fi][rg] - g0 - sgn * gn) * invn;
        }
      }
    }
  }
}

// coarsest map: y = x @ T0_w^T + T0_b
__global__ void t0_k(const float* __restrict__ xin, const float* __restrict__ w,
                     const float* __restrict__ bv, float* __restrict__ xout) {
  int idx = blockIdx.x * blockDim.x + threadIdx.x;
  if (idx >= BB * CC * KK) return;
  int k = idx & 3;
  int bc = idx >> 2;
  float a = bv[k];
  #pragma unroll
  for (int kp = 0; kp < 4; kp++) a = fmaf(xin[bc*4 + kp], w[k*4 + kp], a);
  xout[idx] = a;
}

__global__ void recon_k(const float* __restrict__ xin, const float* __restrict__ usl,
                        const float* __restrict__ udl,
                        const float* __restrict__ rce, const float* __restrict__ rco,
                        float* __restrict__ xout, int nh) {
  int idx = blockIdx.x * blockDim.x + threadIdx.x;
  if (idx >= BB * nh * CC) return;
  int c = idx & (CC - 1);
  int t = idx / CC;
  int j = t % nh;
  int b = t / nh;
  size_t ib = (((size_t)b * nh + j) * CC + c) * KK;
  float4 xv = *(const float4*)(xin + ib);
  float4 uv = *(const float4*)(usl + ib);
  float4 dv = *(const float4*)(udl + ib);
  float xx[8] = {xv.x+uv.x, xv.y+uv.y, xv.z+uv.z, xv.w+uv.w, dv.x, dv.y, dv.z, dv.w};
  float ev[4] = {0.f,0.f,0.f,0.f}, ov[4] = {0.f,0.f,0.f,0.f};
  #pragma unroll
  for (int p = 0; p < 8; p++) {
    float v = xx[p];
    #pragma unroll
    for (int k = 0; k < 4; k++) {
      ev[k] = fmaf(v, rce[p*4+k], ev[k]);
      ov[k] = fmaf(v, rco[p*4+k], ov[k]);
    }
  }
  size_t ob = (((size_t)b * (2*nh) + 2*j) * CC + c) * KK;
  *(float4*)(xout + ob) = make_float4(ev[0], ev[1], ev[2], ev[3]);
  *(float4*)(xout + ob + CC*KK) = make_float4(ov[0], ov[1], ov[2], ov[3]);
}

extern "C" void kernel_launch(void* const* d_in, const int* in_sizes, int n_in,
                              void* d_out, int out_size, void* d_ws, size_t ws_size,
                              hipStream_t stream) {
  const float* x   = (const float*)d_in[0];
  const float* wAr = (const float*)d_in[1];
  const float* wAi = (const float*)d_in[2];
  const float* wBr = (const float*)d_in[3];
  const float* wBi = (const float*)d_in[4];
  const float* wCr = (const float*)d_in[5];
  const float* wCi = (const float*)d_in[6];
  const float *ecs, *ecd, *rce, *rco, *t0w, *t0b;
  if (in_sizes[7] == 16) {
    t0w = (const float*)d_in[7];  t0b = (const float*)d_in[8];
    ecs = (const float*)d_in[9];  ecd = (const float*)d_in[10];
    rce = (const float*)d_in[11]; rco = (const float*)d_in[12];
  } else {
    ecs = (const float*)d_in[7];  ecd = (const float*)d_in[8];
    rce = (const float*)d_in[9];  rco = (const float*)d_in[10];
    t0w = (const float*)d_in[11]; t0b = (const float*)d_in[12];
  }

  int nh[NLEV], lv[NLEV];
  size_t twoff[NLEV], spoff[NLEV];
  size_t tacc = 0, spacc = 0;
  for (int q = 0; q < NLEV; q++) {
    nh[q] = NN >> (q + 1);
    int li = nh[q] / 2 + 1;
    lv[q] = li < AL ? li : AL;
    twoff[q] = tacc; tacc += (size_t)nh[q] * lv[q];
    spoff[q] = spacc; spacc += (size_t)BB * CKD * lv[q];
  }

  float* ws = (float*)d_ws;
  const size_t XS = (size_t)BB * (NN/2) * CKD;     // 8,388,608 floats
  float*  xb0  = ws;                               // XS floats
  float*  xb1  = xb0 + XS;                         // XS/2 floats (recon even-q outputs fit EXACTLY)
  float2* Dall = (float2*)(xb1 + XS / 2);          // spacc float2, fwd spectra [b][m][i]; later Gt4
  float2* Sall = Dall + spacc;
  float2* Uall = Sall + spacc;                     // 4 u16 planes (mix out) / fwd scrD
  float2* Vall = Uall + spacc;
  float*  udT  = (float*)(Vall + spacc);           // XS floats: fwd dh/dl; Wt planes; recon ud
  float*  usT  = udT + XS;                         // XS floats: fwd sh/sl; recon us; t0buf tail
  // inverse twiddle planes [j][m] (sin negated), 4 x tacc u16 (lo planes unused by v3)
  u16* tjch = (u16*)(usT + XS);
  u16* tjcl = tjch + tacc;
  u16* tjsh = tjcl + tacc;
  u16* tjsl = tjsh + tacc;
  // forward twiddle planes [m][j], 4 x tacc u16
  u16* twCh = tjsl + tacc;
  u16* twCl = twCh + tacc;
  u16* twSh = twCl + tacc;
  u16* twSl = twSh + tacc;
  // bf16 source planes: [b][CKD][n], level-0 sized
  u16* dhp = (u16*)udT;
  u16* dlp = dhp + (size_t)BB * CKD * (NN/2);
  u16* shp = (u16*)usT;
  u16* slp = shp + (size_t)BB * CKD * (NN/2);
  float2* scrD = Uall;                             // fwd K-split D partials
  u16* WtP = (u16*)udT;                            // 6 bf16 weight planes [m][o][i] (mix time), 25.2 MB
  u16* Up4 = (u16*)Uall;                           // mix output: 4 planes [b][m][o]
  u16* Gt4 = (u16*)Dall;                           // transposed G: 4 planes [b][o][m] — survives to q=0
  float* t0buf = usT + XS - 4096;                  // 2048 floats; dead tail of usT

  LevTab lt;
  for (int q = 0; q < NLEV; q++) { lt.off[q] = (int)twoff[q]; lt.n[q] = nh[q]; lt.l[q] = lv[q]; }
  lt.total = (int)tacc;
  twiddle_fill_k<<<dim3((unsigned)((tacc + 255) / 256)), 256, 0, stream>>>(
      tjch, tjcl, tjsh, tjsl, twCh, twCl, twSh, twSl, lt);

  // ---------- decompose(+transpose/convert) + MFMA forward DFT ----------
  const float* cur = x;
  float* nxt = xb0;
  for (int q = 0; q < NLEV; q++) {
    int n2 = nh[q], l = lv[q];
    decomp_t_k<<<dim3((n2 + 63) / 64, BB), 256, 0, stream>>>(cur, nxt, dhp, dlp, shp, slp,
                                                             ecs, ecd, n2);
    int P = (n2 >= 512) ? 8 : ((n2 >= 64) ? n2 / 64 : 1);
    int chunk = ((n2 + P - 1) / P + 31) & ~31;
    int mtiles = (l + 63) / 64;
    float* curbuf = (q == 0) ? xb1 : ((q & 1) ? xb0 : xb1);
    float2* Dp = (P > 1) ? scrD : (Dall + spoff[q]);
    float2* Sp = (P > 1) ? (float2*)curbuf : (Sall + spoff[q]);
    fwd_mfma_k<<<dim3(mtiles, BB, 2 * P), 256, 0, stream>>>(
        dhp, dlp, shp, slp,
        twCh + twoff[q], twCl + twoff[q], twSh + twoff[q], twSl + twoff[q],
        Dp, Sp, n2, l, P, chunk);
    if (P > 1) {
      int cnt4 = (BB * CKD * l) / 2;
      reduce_k<<<dim3((2 * cnt4 + 255) / 256), 256, 0, stream>>>(
          (float4*)(Dall + spoff[q]), (float4*)(Sall + spoff[q]),
          (const float4*)scrD, (const float4*)Sp, cnt4, P);
    }
    cur = nxt;
    nxt = (nxt == xb0) ? xb1 : xb0;
  }

  // ---------- transpose+convert weights into 6 bf16 planes [m][o][i] ----------
  wtr_k<<<dim3(CKD, AL / 32, 3), 256, 0, stream>>>(wAr, wAi, wBr, wBi, wCr, wCi, WtP);

  // ---------- batched per-(lev,m) MFMA mode-mix ----------
  MixTab2 mt;
  int mc = 0;
  for (int q = 0; q < NLEV; q++) {
    mt.off[q] = (long long)spoff[q];
    mt.l[q] = lv[q];
    mt.mcum[q] = mc;
    mc += lv[q];
  }
  mix3_k<<<dim3((unsigned)mc, 2), 256, 0, stream>>>(Dall, Sall, WtP,
                                                    Up4, (long long)spacc, mt);

  // ---------- transpose G planes [b][m][o] -> [b][o][m] (Dall/Sall dead post-mix) ----------
  gt_k<<<dim3(NLEV * BB, 4), 256, 0, stream>>>(Up4, Gt4, (long long)spacc, mt);

  // ---------- coarsest linear map (to usT-tail scratch; xb0/xb1 reserved for recon) ----------
  t0_k<<<dim3((BB * CC * KK + 255) / 256), 256, 0, stream>>>(cur, t0w, t0b, t0buf);

  // ---------- reconstruct (MFMA inverse DFT per level) ----------
  const float* rcur = t0buf;
  for (int q = NLEV - 1; q >= 0; q--) {
    int n2 = nh[q], l = lv[q];
    int nyq = (((n2 & 1) == 0) && (l == n2 / 2 + 1)) ? 1 : 0;
    inv_mfma_k<<<dim3((n2 + 63) / 64, BB, 2), 256, 0, stream>>>(
        Gt4 + spoff[q], Gt4 + 2 * spacc + spoff[q], (long long)spacc,
        tjch + twoff[q], tjsh + twoff[q],
        udT, usT, n2, l, nyq);
    float* outp = (q == 0) ? (float*)d_out : ((q & 1) ? xb0 : xb1);
    int tot = BB * n2 * CC;
    recon_k<<<dim3((tot + 255) / 256), 256, 0, stream>>>(rcur, usT, udT,
                                                         rce, rco, outp, n2);
    rcur = outp;
  }
}